// Round 12
// baseline (489.578 us; speedup 1.0000x reference)
//
#include <hip/hip_runtime.h>
#include <hip/hip_bf16.h>
#include <math.h>

// Problem constants
#define B_ 2
#define T_ 2048
#define C_ 2048
#define H_ 16
#define HD_ 128
#define LORA_ 512
#define RD_ 64
#define ND_ 64
#define BT_ (B_*T_)            // 4096
#define NKVA_ 576              // LORA + RD
#define NKVAP_ 640             // padded to 128
#define LOG2_THETA 16.609640474436812f

typedef __bf16 bf16x8 __attribute__((ext_vector_type(8)));
typedef float  f32x4  __attribute__((ext_vector_type(4)));

#define MFMA16(a,b,c) __builtin_amdgcn_mfma_f32_16x16x32_bf16((a),(b),(c),0,0,0)

// global -> LDS direct 16B copy (lds dest must be wave-uniform base + lane*16)
__device__ static inline void load_lds16(const __bf16* g, __bf16* l) {
  auto* lp = (__attribute__((address_space(3))) char*)(uintptr_t)(l);
  auto* gp = (const __attribute__((address_space(1))) char*)(g);
  __builtin_amdgcn_global_load_lds(gp, lp, 16, 0, 0);
}

__device__ static inline unsigned pkbf(float a, float b) {
  union { __bf16 h[2]; unsigned u; } v;
  v.h[0] = (__bf16)a; v.h[1] = (__bf16)b;
  return v.u;
}

// ---------------------------------------------------------------- casts
__global__ __launch_bounds__(256) void k_cast_x(const float* __restrict__ x,
                                                __bf16* __restrict__ xb, int n) {
  int idx = blockIdx.x * 256 + threadIdx.x;
  if (idx < n) xb[idx] = (__bf16)x[idx];
}

// dst[n][k] = src[k][n]; src (K,N) f32, dst (NP,K) bf16, zero-fill n in [N,NP)
__global__ __launch_bounds__(256) void k_tcast(const float* __restrict__ src,
                                               __bf16* __restrict__ dst,
                                               int K, int N, int NP) {
  __shared__ float tile[32][33];
  int k0 = blockIdx.x * 32;
  int n0 = blockIdx.y * 32;
  int tx = threadIdx.x & 31, ty = threadIdx.x >> 5;
  for (int i = ty; i < 32; i += 8) {
    int n = n0 + tx;
    tile[i][tx] = (n < N) ? src[(size_t)(k0 + i) * N + n] : 0.0f;
  }
  __syncthreads();
  for (int i = ty; i < 32; i += 8) {
    dst[(size_t)(n0 + i) * K + k0 + tx] = (__bf16)tile[tx][i];
  }
}

// dst[n][kc] = Wo[(kc>>6)*128 + (kc&63)][n]; dst (2048,1024) bf16
__global__ __launch_bounds__(256) void k_tcast_wo(const float* __restrict__ Wo,
                                                  __bf16* __restrict__ dst) {
  __shared__ float tile[32][33];
  int kc0 = blockIdx.x * 32;
  int n0  = blockIdx.y * 32;
  int rbase = (kc0 >> 6) * 128 + (kc0 & 63);
  int tx = threadIdx.x & 31, ty = threadIdx.x >> 5;
  for (int i = ty; i < 32; i += 8)
    tile[i][tx] = Wo[(size_t)(rbase + i) * C_ + n0 + tx];
  __syncthreads();
  for (int i = ty; i < 32; i += 8)
    dst[(size_t)(n0 + i) * 1024 + kc0 + tx] = (__bf16)tile[tx][i];
}

// ---------------------------------------------------------------- GEMM
// R8-verified (334.9 us total): 128x128 tile, BK=32, 4 waves, 256 threads,
// double-buffered global_load_lds staging. R10's 512-thread split-K variant
// was neutral (335.9) -> keep the simpler one.
__global__ __launch_bounds__(256) void k_gemm_bt(const __bf16* __restrict__ A,
                                                 const __bf16* __restrict__ B,
                                                 float* __restrict__ C,
                                                 int M, int N, int K) {
  __shared__ __align__(16) __bf16 As[2][128 * 32];
  __shared__ __align__(16) __bf16 Bs[2][128 * 32];
  const int tid  = threadIdx.x;
  const int lane = tid & 63;
  const int wave = tid >> 6;
  const int bm = blockIdx.x, bn = blockIdx.y;
  const int r0 = tid >> 2;
  const int c8 = (tid & 3) * 8;
  const __bf16* Ag = A + (size_t)(bm * 128 + r0) * K + c8;
  const __bf16* Bg = B + (size_t)(bn * 128 + r0) * K + c8;
  const int wr = (wave >> 1) * 64, wc = (wave & 1) * 64;
  const int fr = lane & 15, fk = (lane >> 4) * 8;
  const f32x4 fzero = {0.f, 0.f, 0.f, 0.f};
  f32x4 acc[4][4];
#pragma unroll
  for (int i = 0; i < 4; ++i)
#pragma unroll
    for (int j = 0; j < 4; ++j) acc[i][j] = fzero;

  // stage tile 0 into buf 0
  load_lds16(Ag,                  &As[0][tid * 8]);
  load_lds16(Ag + (size_t)64 * K, &As[0][tid * 8 + 2048]);
  load_lds16(Bg,                  &Bs[0][tid * 8]);
  load_lds16(Bg + (size_t)64 * K, &Bs[0][tid * 8 + 2048]);

  int buf = 0;
  for (int k0 = 0; k0 < K; k0 += 32) {
    __syncthreads();   // drains own vmcnt -> buf's staging complete for all
    if (k0 + 32 < K) {
      const int nb = buf ^ 1;
      load_lds16(Ag + k0 + 32,                  &As[nb][tid * 8]);
      load_lds16(Ag + (size_t)64 * K + k0 + 32, &As[nb][tid * 8 + 2048]);
      load_lds16(Bg + k0 + 32,                  &Bs[nb][tid * 8]);
      load_lds16(Bg + (size_t)64 * K + k0 + 32, &Bs[nb][tid * 8 + 2048]);
    }
    bf16x8 af[4], bfg[4];
#pragma unroll
    for (int i = 0; i < 4; ++i) af[i]  = *(const bf16x8*)&As[buf][(wr + i * 16 + fr) * 32 + fk];
#pragma unroll
    for (int j = 0; j < 4; ++j) bfg[j] = *(const bf16x8*)&Bs[buf][(wc + j * 16 + fr) * 32 + fk];
#pragma unroll
    for (int i = 0; i < 4; ++i)
#pragma unroll
      for (int j = 0; j < 4; ++j)
        acc[i][j] = MFMA16(af[i], bfg[j], acc[i][j]);
    buf ^= 1;
  }
  const int rbase = (lane >> 4) * 4;
  float* Cb = C + (size_t)(bm * 128 + wr + rbase) * N + bn * 128 + wc + fr;
#pragma unroll
  for (int i = 0; i < 4; ++i)
#pragma unroll
    for (int j = 0; j < 4; ++j)
#pragma unroll
      for (int r = 0; r < 4; ++r)
        Cb[(size_t)(i * 16 + r) * N + j * 16] = acc[i][j][r];
}

// ---------------------------------------------------------------- rope
// q (BT,2048) f32 -> qf [b][h][t][128] bf16, rope on d in [64,128)
// NOTE: q is pre-scaled by log2(e)/sqrt(HD) here so the attention kernel can
// feed MFMA results straight into exp2f with no per-element multiply.
__global__ __launch_bounds__(256) void k_rope_q(const float* __restrict__ q,
                                                __bf16* __restrict__ qf) {
  const float scale2 = 1.4426950408889634f / 11.313708498984760f; // log2e/sqrt(128)
  int idx = blockIdx.x * 256 + threadIdx.x;   // over B*H*T*HD = 8388608
  int d  = idx & 127;
  int t  = (idx >> 7) & 2047;
  int bh = idx >> 18;
  int h  = bh & 15, b = bh >> 4;
  const float* qrow = q + ((size_t)(b * T_ + t)) * 2048 + h * 128;
  float v;
  if (d < 64) {
    v = qrow[d];
  } else {
    int i = (d - 64) >> 1;
    float freq = exp2f(-((float)(2 * i) / 64.0f) * LOG2_THETA);
    float ang = (float)t * freq;
    float c = cosf(ang), s = sinf(ang);
    float x0 = qrow[64 + 2 * i], x1 = qrow[64 + 2 * i + 1];
    v = (d & 1) ? (x0 * s + x1 * c) : (x0 * c - x1 * s);
  }
  qf[idx] = (__bf16)(v * scale2);
}

// Fragment-packed K layout (consumed by the no-LDS attention kernel):
//   Kp[bh][tile][cg][kg][lane][8 bf16], tile = key>>6, cg = (key>>4)&3,
//   fr = key&15, kg = dim>>5, quad = (dim>>3)&3, e = dim&7, lane = quad*16+fr.
// Vp[bh][tile][g][ks][lane][8]: dim row = g*16+fr, key col = ks*32+quad*8+e.

// ckv (BT,640) f32 cols [512,576) -> Kp rope dims (64..127), dup per h
__global__ __launch_bounds__(256) void k_rope_kf(const float* __restrict__ ckv,
                                                 __bf16* __restrict__ Kp) {
  int idx = blockIdx.x * 256 + threadIdx.x;   // over B*H*T*32 = 2097152 (pairs)
  int i = idx & 31;            // rope pair index: dims 64+2i, 64+2i+1
  int t = (idx >> 5) & 2047;
  int h = (idx >> 16) & 15;
  int b = idx >> 20;
  const float* src = ckv + ((size_t)(b * T_ + t)) * NKVAP_ + 512;
  float freq = exp2f(-((float)(2 * i) / 64.0f) * LOG2_THETA);
  float ang = (float)t * freq;
  float c = cosf(ang), s = sinf(ang);
  float x0 = src[2 * i], x1 = src[2 * i + 1];
  float v0 = x0 * c - x1 * s;
  float v1 = x0 * s + x1 * c;
  int bh = b * 16 + h;
  int tile = t >> 6, cg = (t >> 4) & 3, frk = t & 15;
  int kg = 2 + (i >> 4), qd = (i >> 2) & 3, e = (2 * i) & 7;
  size_t off = (((size_t)(bh * 32 + tile) * 16) + cg * 4 + kg) * 512
             + (qd * 16 + frk) * 8 + e;
  *(unsigned*)(Kp + off) = pkbf(v0, v1);
}

__global__ __launch_bounds__(256) void k_cast_kvl(const float* __restrict__ ckv,
                                                  __bf16* __restrict__ kvl) {
  int idx = blockIdx.x * 256 + threadIdx.x;   // over BT*512
  int r = idx >> 9, c = idx & 511;
  kvl[idx] = (__bf16)ckv[(size_t)r * NKVAP_ + c];
}

// kv (BT,1024) f32 -> Kp nope dims (0..63) AND Vp, one read of kv
__global__ __launch_bounds__(256) void k_pack_kv(const float* __restrict__ kv,
                                                 __bf16* __restrict__ Kp,
                                                 __bf16* __restrict__ Vp) {
  __shared__ float tile[64][65];
  const int bh = blockIdx.x;
  const int b = bh >> 4, h = bh & 15;
  const int t0 = blockIdx.y * 64;
  const int tilei = t0 >> 6;
  const int tid = threadIdx.x;
  const int i0 = tid >> 4, d4 = (tid & 15) * 4;
  const int kg = d4 >> 5, qd = (d4 >> 3) & 3, e = d4 & 7;   // dim coords
#pragma unroll
  for (int p = 0; p < 4; ++p) {
    int i = i0 + p * 16;                                    // key within tile
    const float* src = kv + ((size_t)(b * T_ + t0 + i)) * 1024 + h * 64 + d4;
    float4 v = *(const float4*)src;
    tile[i][d4] = v.x; tile[i][d4 + 1] = v.y; tile[i][d4 + 2] = v.z; tile[i][d4 + 3] = v.w;
    union { __bf16 hh[4]; uint2 u; } o;
    o.hh[0] = (__bf16)v.x; o.hh[1] = (__bf16)v.y; o.hh[2] = (__bf16)v.z; o.hh[3] = (__bf16)v.w;
    const int cg = i >> 4, frk = i & 15;
    size_t koff = (((size_t)(bh * 32 + tilei) * 16) + cg * 4 + kg) * 512
                + (qd * 16 + frk) * 8 + e;
    *(uint2*)(Kp + koff) = o.u;
  }
  __syncthreads();
  const int dd = tid >> 2, tc0 = (tid & 3) * 16;
  __bf16 outv[16];
#pragma unroll
  for (int j = 0; j < 16; ++j) outv[j] = (__bf16)tile[tc0 + j][dd];
  const int g = dd >> 4, frv = dd & 15;
  const int ks = tc0 >> 5, qv = (tc0 >> 3) & 3;
  size_t voff = (((size_t)(bh * 32 + tilei) * 8) + g * 2 + ks) * 512
              + (qv * 16 + frv) * 8;
  *(bf16x8*)(Vp + voff) = *(bf16x8*)&outv[0];
  *(bf16x8*)(Vp + voff + 128) = *(bf16x8*)&outv[8];   // quad+1 -> +16*8 halfwords
}

// ---------------------------------------------------------------- attention
// R11 = R7 split-K + T14 K-prefetch rotation. The 16 K-fragment loads were at
// the loop head, fully latency-exposed before QK^T (42% memory-wait, MfmaUtil
// 15.7%). Now: QK^T consumes kr -> V loads issued -> kr RELOADED with the
// NEXT tile's fragments (same registers, WAR handled by scoreboard, zero
// extra VGPR) -> softmax+PV cover both load batches' latency. Next iter's
// QK^T finds kr resident. Same technique that gave +17% in m214 v27.
__global__ __launch_bounds__(512, 4) void k_attn(const __bf16* __restrict__ qf,
                                                 const __bf16* __restrict__ Kp,
                                                 const __bf16* __restrict__ Vp,
                                                 __bf16* __restrict__ yc) {
  const int blk = blockIdx.x;          // 1024 = 32 qt * 32 bh
  const int bh = blk & 31;             // bh mod 8 == XCD -> per-XCD L2 locality
  const int qt = 31 - (blk >> 5);      // heavy tiles first
  const int b = bh >> 4, h = bh & 15;
  const int qbase = qt * 64;
  const int tid = threadIdx.x;
  const int lane = tid & 63, wave = tid >> 6;    // 0..7
  const int w4 = wave & 3, par = wave >> 2;      // q-row group, K-tile parity
  const int fr = lane & 15, quad = lane >> 4, fk8 = quad * 8;

  __shared__ __align__(16) f32x4 mrgO[4][64][4]; // 16 KB partial accO
  __shared__ float mrgML[4][64][2];              // 2 KB partial m,l

  const int qi = qbase + w4 * 16 + fr;           // this lane's q-row
  const __bf16* qb = qf + ((size_t)bh * T_ + qi) * HD_;
  bf16x8 aq[4];
#pragma unroll
  for (int g = 0; g < 4; ++g) aq[g] = *(const bf16x8*)(qb + g * 32 + fk8);

  const f32x4 fzero = {0.f, 0.f, 0.f, 0.f};
  f32x4 accO[4];
#pragma unroll
  for (int g = 0; g < 4; ++g) accO[g] = fzero;
  float m = -1e30f, l = 0.f;

  const __bf16* kb = Kp + (size_t)bh * 32 * 8192 + (size_t)lane * 8;
  const __bf16* vb = Vp + (size_t)bh * 32 * 4096 + (size_t)lane * 8;
  const int srcA = (quad & 1) * 32 + fr, srcB = srcA + 16;
  const int hi = quad >> 1;

  bf16x8 kr[4][4];
  // prologue: load K fragments for this parity's first tile
  if (par * 64 <= qbase) {
    const __bf16* kt0 = kb + (size_t)(par) * 8192;
#pragma unroll
    for (int cg = 0; cg < 4; ++cg)
#pragma unroll
      for (int kg = 0; kg < 4; ++kg)
        kr[cg][kg] = *(const bf16x8*)(kt0 + (cg * 4 + kg) * 512);
  }

  for (int s0 = par * 64; s0 <= qbase; s0 += 128) {
    const __bf16* vt = vb + (size_t)(s0 >> 6) * 4096;

    // S^T: rows = keys (quad*4+r), cols = q (fr); kr loaded last iteration
    f32x4 accST[4];
#pragma unroll
    for (int cg = 0; cg < 4; ++cg) accST[cg] = fzero;
    __builtin_amdgcn_s_setprio(1);
#pragma unroll
    for (int cg = 0; cg < 4; ++cg) {
#pragma unroll
      for (int kg = 0; kg < 4; ++kg)
        accST[cg] = MFMA16(kr[cg][kg], aq[kg], accST[cg]);
    }
    __builtin_amdgcn_s_setprio(0);

    // V fragments for THIS tile; latency hides under softmax
    bf16x8 vr[4][2];
#pragma unroll
    for (int g = 0; g < 4; ++g)
#pragma unroll
      for (int ks = 0; ks < 2; ++ks)
        vr[g][ks] = *(const bf16x8*)(vt + (g * 2 + ks) * 512);

    // T14: prefetch NEXT tile's K fragments into the same registers (WAR on
    // the just-issued MFMAs is resolved by the scoreboard; zero extra VGPR).
    // Latency hides under softmax + PV of this tile.
    if (s0 + 128 <= qbase) {
      const __bf16* ktn = kb + (size_t)((s0 >> 6) + 2) * 8192;
#pragma unroll
      for (int cg = 0; cg < 4; ++cg)
#pragma unroll
        for (int kg = 0; kg < 4; ++kg)
          kr[cg][kg] = *(const bf16x8*)(ktn + (cg * 4 + kg) * 512);
    }

    // row max (mask only on the diagonal tile; values pre-scaled via qf)
    float lmax = -1e30f;
    if (s0 == qbase) {
#pragma unroll
      for (int cg = 0; cg < 4; ++cg) {
#pragma unroll
        for (int r = 0; r < 4; ++r) {
          const int key = s0 + cg * 16 + quad * 4 + r;
          float v = accST[cg][r];
          v = (key <= qi) ? v : -1e30f;
          accST[cg][r] = v;
          lmax = fmaxf(lmax, v);
        }
      }
    } else {
#pragma unroll
      for (int cg = 0; cg < 4; ++cg) {
#pragma unroll
        for (int r = 0; r < 4; ++r) lmax = fmaxf(lmax, accST[cg][r]);
      }
    }
    lmax = fmaxf(lmax, __shfl_xor(lmax, 16, 64));
    lmax = fmaxf(lmax, __shfl_xor(lmax, 32, 64));

    // T13 defer-max: only rescale when the running max grew by > 8
    if (!__all(lmax <= m + 8.0f)) {
      const float mn = fmaxf(m, lmax);
      const float alpha = exp2f(m - mn);
      l *= alpha;
#pragma unroll
      for (int g = 0; g < 4; ++g)
#pragma unroll
        for (int r = 0; r < 4; ++r) accO[g][r] *= alpha;
      m = mn;
    }

    float lsum = 0.f;
    unsigned pk0[4], pk1[4];
#pragma unroll
    for (int cg = 0; cg < 4; ++cg) {
      float p0 = exp2f(accST[cg][0] - m);
      float p1 = exp2f(accST[cg][1] - m);
      float p2 = exp2f(accST[cg][2] - m);
      float p3 = exp2f(accST[cg][3] - m);
      lsum += (p0 + p1) + (p2 + p3);
      pk0[cg] = pkbf(p0, p1);
      pk1[cg] = pkbf(p2, p3);
    }
    lsum += __shfl_xor(lsum, 16, 64);
    lsum += __shfl_xor(lsum, 32, 64);
    l += lsum;

    // PV: B-operand (P) built from register shuffles
#pragma unroll
    for (int ks = 0; ks < 2; ++ks) {
      int a0 = __shfl((int)pk0[2 * ks], srcA, 64);
      int b0 = __shfl((int)pk0[2 * ks + 1], srcA, 64);
      int a1 = __shfl((int)pk1[2 * ks], srcA, 64);
      int b1 = __shfl((int)pk1[2 * ks + 1], srcA, 64);
      int a2 = __shfl((int)pk0[2 * ks], srcB, 64);
      int b2 = __shfl((int)pk0[2 * ks + 1], srcB, 64);
      int a3 = __shfl((int)pk1[2 * ks], srcB, 64);
      int b3 = __shfl((int)pk1[2 * ks + 1], srcB, 64);
      union { int i[4]; bf16x8 v; } pf;
      pf.i[0] = hi ? b0 : a0;
      pf.i[1] = hi ? b1 : a1;
      pf.i[2] = hi ? b2 : a2;
      pf.i[3] = hi ? b3 : a3;
      __builtin_amdgcn_s_setprio(1);
#pragma unroll
      for (int g = 0; g < 4; ++g)
        accO[g] = MFMA16(vr[g][ks], pf.v, accO[g]);
      __builtin_amdgcn_s_setprio(0);
    }
  }

  // split-K merge: odd-parity waves publish partials, even-parity merge+store
  if (par) {
#pragma unroll
    for (int g = 0; g < 4; ++g) mrgO[w4][lane][g] = accO[g];
    mrgML[w4][lane][0] = m;
    mrgML[w4][lane][1] = l;
  }
  __syncthreads();
  if (!par) {
    const float m1 = mrgML[w4][lane][0];
    const float l1 = mrgML[w4][lane][1];
    const float mn = fmaxf(m, m1);
    const float a0 = exp2f(m - mn), a1 = exp2f(m1 - mn);
    const float lt = l * a0 + l1 * a1;
    const float linv = 1.0f / lt;
    // epilogue: O^T -> yc[(b*T+qi)*1024 + h*64 + d], d = g*16 + quad*4 + r
    __bf16* yb = yc + ((size_t)(b * T_ + qi)) * 1024 + h * 64 + quad * 4;
#pragma unroll
    for (int g = 0; g < 4; ++g) {
      f32x4 o1 = mrgO[w4][lane][g];
      union { unsigned u[2]; uint2 v; } o;
      o.u[0] = pkbf((accO[g][0] * a0 + o1[0] * a1) * linv,
                    (accO[g][1] * a0 + o1[1] * a1) * linv);
      o.u[1] = pkbf((accO[g][2] * a0 + o1[2] * a1) * linv,
                    (accO[g][3] * a0 + o1[3] * a1) * linv);
      *(uint2*)(yb + g * 16) = o.v;
    }
  }
}

// ---------------------------------------------------------------- launch
extern "C" void kernel_launch(void* const* d_in, const int* in_sizes, int n_in,
                              void* d_out, int out_size, void* d_ws, size_t ws_size,
                              hipStream_t stream) {
  const float* x    = (const float*)d_in[0];
  const float* Wq   = (const float*)d_in[1];
  const float* Wkva = (const float*)d_in[2];
  const float* Wkvb = (const float*)d_in[3];
  const float* Wo   = (const float*)d_in[4];
  float* out = (float*)d_out;
  char* ws = (char*)d_ws;

  // workspace layout (bytes)
  size_t off = 0;
  __bf16* xb    = (__bf16*)(ws + off); off += (size_t)BT_ * C_ * 2;          // 16.78M
  __bf16* WqT   = (__bf16*)(ws + off); off += (size_t)2048 * 2048 * 2;       // 8.39M
  __bf16* WkvaT = (__bf16*)(ws + off); off += (size_t)NKVAP_ * 2048 * 2;     // 2.62M
  __bf16* WkvbT = (__bf16*)(ws + off); off += (size_t)1024 * 512 * 2;        // 1.05M
  __bf16* WoTc  = (__bf16*)(ws + off); off += (size_t)2048 * 1024 * 2;       // 4.19M
  float*  q     = (float*)(ws + off);  off += (size_t)BT_ * 2048 * 4;        // 33.55M
  float*  ckv   = (float*)(ws + off);  off += (size_t)BT_ * NKVAP_ * 4;      // 10.49M
  __bf16* kvl   = (__bf16*)(ws + off); off += (size_t)BT_ * 512 * 2;         // 4.19M
  float*  kv    = (float*)(ws + off);  off += (size_t)BT_ * 1024 * 4;        // 16.78M
  __bf16* qfb   = (__bf16*)(ws + off); off += (size_t)B_ * H_ * T_ * HD_ * 2;// 16.78M
  __bf16* yc    = (__bf16*)(ws + off); off += (size_t)BT_ * 1024 * 2;        // 8.39M
  // Kp (16.78M) and Vp (8.39M) alias q's 33.55M buffer: q is dead after
  // k_rope_q, and both are written strictly after k_rope_q in stream order.
  __bf16* Kp = (__bf16*)q;
  __bf16* Vp = (__bf16*)((char*)q + (size_t)B_ * H_ * T_ * HD_ * 2);

  // 1. casts / transposes
  k_cast_x<<<(BT_ * C_) / 256, 256, 0, stream>>>(x, xb, BT_ * C_);
  k_tcast<<<dim3(2048 / 32, 2048 / 32), 256, 0, stream>>>(Wq, WqT, 2048, 2048, 2048);
  k_tcast<<<dim3(2048 / 32, NKVAP_ / 32), 256, 0, stream>>>(Wkva, WkvaT, 2048, NKVA_, NKVAP_);
  k_tcast<<<dim3(512 / 32, 1024 / 32), 256, 0, stream>>>(Wkvb, WkvbT, 512, 1024, 1024);
  k_tcast_wo<<<dim3(1024 / 32, 2048 / 32), 256, 0, stream>>>(Wo, WoTc);

  // 2. projections
  k_gemm_bt<<<dim3(BT_ / 128, 2048 / 128), 256, 0, stream>>>(xb, WqT, q, BT_, 2048, 2048);
  k_gemm_bt<<<dim3(BT_ / 128, NKVAP_ / 128), 256, 0, stream>>>(xb, WkvaT, ckv, BT_, NKVAP_, 2048);

  // 3. rope + casts (q buffer dead after k_rope_q)
  k_rope_q<<<(B_ * H_ * T_ * HD_) / 256, 256, 0, stream>>>(q, qfb);
  k_cast_kvl<<<(BT_ * 512) / 256, 256, 0, stream>>>(ckv, kvl);

  // 4. kv up-projection, then pack Kp (nope+rope) and Vp
  k_gemm_bt<<<dim3(BT_ / 128, 1024 / 128), 256, 0, stream>>>(kvl, WkvbT, kv, BT_, 1024, 512);
  k_pack_kv<<<dim3(B_ * H_, T_ / 64), 256, 0, stream>>>(kv, Kp, Vp);
  k_rope_kf<<<(B_ * H_ * T_ * 32) / 256, 256, 0, stream>>>(ckv, Kp);

  // 5. attention (1024 blocks x 512 threads; split-K pairs of waves)
  k_attn<<<(T_ / 64) * B_ * H_, 512, 0, stream>>>(qfb, Kp, Vp, yc);

  // 6. output projection
  k_gemm_bt<<<dim3(BT_ / 128, 2048 / 128), 256, 0, stream>>>(yc, WoTc, out, BT_, 2048, 1024);
}

// Round 13
// 337.357 us; speedup vs baseline: 1.4512x; 1.4512x over previous
//
#include <hip/hip_runtime.h>
#include <hip/hip_bf16.h>
#include <math.h>

// Problem constants
#define B_ 2
#define T_ 2048
#define C_ 2048
#define H_ 16
#define HD_ 128
#define LORA_ 512
#define RD_ 64
#define ND_ 64
#define BT_ (B_*T_)            // 4096
#define NKVA_ 576              // LORA + RD
#define NKVAP_ 640             // padded to 128
#define LOG2_THETA 16.609640474436812f

typedef __bf16 bf16x8 __attribute__((ext_vector_type(8)));
typedef float  f32x4  __attribute__((ext_vector_type(4)));

#define MFMA16(a,b,c) __builtin_amdgcn_mfma_f32_16x16x32_bf16((a),(b),(c),0,0,0)

// global -> LDS direct 16B copy (lds dest must be wave-uniform base + lane*16)
__device__ static inline void load_lds16(const __bf16* g, __bf16* l) {
  auto* lp = (__attribute__((address_space(3))) char*)(uintptr_t)(l);
  auto* gp = (const __attribute__((address_space(1))) char*)(g);
  __builtin_amdgcn_global_load_lds(gp, lp, 16, 0, 0);
}

__device__ static inline unsigned pkbf(float a, float b) {
  union { __bf16 h[2]; unsigned u; } v;
  v.h[0] = (__bf16)a; v.h[1] = (__bf16)b;
  return v.u;
}

// ---------------------------------------------------------------- casts
__global__ __launch_bounds__(256) void k_cast_x(const float* __restrict__ x,
                                                __bf16* __restrict__ xb, int n) {
  int idx = blockIdx.x * 256 + threadIdx.x;
  if (idx < n) xb[idx] = (__bf16)x[idx];
}

// dst[n][k] = src[k][n]; src (K,N) f32, dst (NP,K) bf16, zero-fill n in [N,NP)
__global__ __launch_bounds__(256) void k_tcast(const float* __restrict__ src,
                                               __bf16* __restrict__ dst,
                                               int K, int N, int NP) {
  __shared__ float tile[32][33];
  int k0 = blockIdx.x * 32;
  int n0 = blockIdx.y * 32;
  int tx = threadIdx.x & 31, ty = threadIdx.x >> 5;
  for (int i = ty; i < 32; i += 8) {
    int n = n0 + tx;
    tile[i][tx] = (n < N) ? src[(size_t)(k0 + i) * N + n] : 0.0f;
  }
  __syncthreads();
  for (int i = ty; i < 32; i += 8) {
    dst[(size_t)(n0 + i) * K + k0 + tx] = (__bf16)tile[tx][i];
  }
}

// dst[n][kc] = Wo[(kc>>6)*128 + (kc&63)][n]; dst (2048,1024) bf16
__global__ __launch_bounds__(256) void k_tcast_wo(const float* __restrict__ Wo,
                                                  __bf16* __restrict__ dst) {
  __shared__ float tile[32][33];
  int kc0 = blockIdx.x * 32;
  int n0  = blockIdx.y * 32;
  int rbase = (kc0 >> 6) * 128 + (kc0 & 63);
  int tx = threadIdx.x & 31, ty = threadIdx.x >> 5;
  for (int i = ty; i < 32; i += 8)
    tile[i][tx] = Wo[(size_t)(rbase + i) * C_ + n0 + tx];
  __syncthreads();
  for (int i = ty; i < 32; i += 8)
    dst[(size_t)(n0 + i) * 1024 + kc0 + tx] = (__bf16)tile[tx][i];
}

// ---------------------------------------------------------------- GEMM
// R8-verified (334.9 us total): 128x128 tile, BK=32, 4 waves, 256 threads,
// double-buffered global_load_lds staging. Measured equal or better than:
// 128x64 tile (R9, -9us), 512-thread in-block split-K (R10, neutral).
__global__ __launch_bounds__(256) void k_gemm_bt(const __bf16* __restrict__ A,
                                                 const __bf16* __restrict__ B,
                                                 float* __restrict__ C,
                                                 int M, int N, int K) {
  __shared__ __align__(16) __bf16 As[2][128 * 32];
  __shared__ __align__(16) __bf16 Bs[2][128 * 32];
  const int tid  = threadIdx.x;
  const int lane = tid & 63;
  const int wave = tid >> 6;
  const int bm = blockIdx.x, bn = blockIdx.y;
  const int r0 = tid >> 2;
  const int c8 = (tid & 3) * 8;
  const __bf16* Ag = A + (size_t)(bm * 128 + r0) * K + c8;
  const __bf16* Bg = B + (size_t)(bn * 128 + r0) * K + c8;
  const int wr = (wave >> 1) * 64, wc = (wave & 1) * 64;
  const int fr = lane & 15, fk = (lane >> 4) * 8;
  const f32x4 fzero = {0.f, 0.f, 0.f, 0.f};
  f32x4 acc[4][4];
#pragma unroll
  for (int i = 0; i < 4; ++i)
#pragma unroll
    for (int j = 0; j < 4; ++j) acc[i][j] = fzero;

  // stage tile 0 into buf 0
  load_lds16(Ag,                  &As[0][tid * 8]);
  load_lds16(Ag + (size_t)64 * K, &As[0][tid * 8 + 2048]);
  load_lds16(Bg,                  &Bs[0][tid * 8]);
  load_lds16(Bg + (size_t)64 * K, &Bs[0][tid * 8 + 2048]);

  int buf = 0;
  for (int k0 = 0; k0 < K; k0 += 32) {
    __syncthreads();   // drains own vmcnt -> buf's staging complete for all
    if (k0 + 32 < K) {
      const int nb = buf ^ 1;
      load_lds16(Ag + k0 + 32,                  &As[nb][tid * 8]);
      load_lds16(Ag + (size_t)64 * K + k0 + 32, &As[nb][tid * 8 + 2048]);
      load_lds16(Bg + k0 + 32,                  &Bs[nb][tid * 8]);
      load_lds16(Bg + (size_t)64 * K + k0 + 32, &Bs[nb][tid * 8 + 2048]);
    }
    bf16x8 af[4], bfg[4];
#pragma unroll
    for (int i = 0; i < 4; ++i) af[i]  = *(const bf16x8*)&As[buf][(wr + i * 16 + fr) * 32 + fk];
#pragma unroll
    for (int j = 0; j < 4; ++j) bfg[j] = *(const bf16x8*)&Bs[buf][(wc + j * 16 + fr) * 32 + fk];
#pragma unroll
    for (int i = 0; i < 4; ++i)
#pragma unroll
      for (int j = 0; j < 4; ++j)
        acc[i][j] = MFMA16(af[i], bfg[j], acc[i][j]);
    buf ^= 1;
  }
  const int rbase = (lane >> 4) * 4;
  float* Cb = C + (size_t)(bm * 128 + wr + rbase) * N + bn * 128 + wc + fr;
#pragma unroll
  for (int i = 0; i < 4; ++i)
#pragma unroll
    for (int j = 0; j < 4; ++j)
#pragma unroll
      for (int r = 0; r < 4; ++r)
        Cb[(size_t)(i * 16 + r) * N + j * 16] = acc[i][j][r];
}

// ---------------------------------------------------------------- rope
// q (BT,2048) f32 -> qf [b][h][t][128] bf16, rope on d in [64,128)
// NOTE: q is pre-scaled by log2(e)/sqrt(HD) here so the attention kernel can
// feed MFMA results straight into exp2f with no per-element multiply.
__global__ __launch_bounds__(256) void k_rope_q(const float* __restrict__ q,
                                                __bf16* __restrict__ qf) {
  const float scale2 = 1.4426950408889634f / 11.313708498984760f; // log2e/sqrt(128)
  int idx = blockIdx.x * 256 + threadIdx.x;   // over B*H*T*HD = 8388608
  int d  = idx & 127;
  int t  = (idx >> 7) & 2047;
  int bh = idx >> 18;
  int h  = bh & 15, b = bh >> 4;
  const float* qrow = q + ((size_t)(b * T_ + t)) * 2048 + h * 128;
  float v;
  if (d < 64) {
    v = qrow[d];
  } else {
    int i = (d - 64) >> 1;
    float freq = exp2f(-((float)(2 * i) / 64.0f) * LOG2_THETA);
    float ang = (float)t * freq;
    float c = cosf(ang), s = sinf(ang);
    float x0 = qrow[64 + 2 * i], x1 = qrow[64 + 2 * i + 1];
    v = (d & 1) ? (x0 * s + x1 * c) : (x0 * c - x1 * s);
  }
  qf[idx] = (__bf16)(v * scale2);
}

// Fragment-packed K layout (consumed by the no-LDS attention kernel):
//   Kp[bh][tile][cg][kg][lane][8 bf16], tile = key>>6, cg = (key>>4)&3,
//   fr = key&15, kg = dim>>5, quad = (dim>>3)&3, e = dim&7, lane = quad*16+fr.
// Vp[bh][tile][g][ks][lane][8]: dim row = g*16+fr, key col = ks*32+quad*8+e.

// ckv (BT,640) f32 cols [512,576) -> Kp rope dims (64..127), dup per h
__global__ __launch_bounds__(256) void k_rope_kf(const float* __restrict__ ckv,
                                                 __bf16* __restrict__ Kp) {
  int idx = blockIdx.x * 256 + threadIdx.x;   // over B*H*T*32 = 2097152 (pairs)
  int i = idx & 31;            // rope pair index: dims 64+2i, 64+2i+1
  int t = (idx >> 5) & 2047;
  int h = (idx >> 16) & 15;
  int b = idx >> 20;
  const float* src = ckv + ((size_t)(b * T_ + t)) * NKVAP_ + 512;
  float freq = exp2f(-((float)(2 * i) / 64.0f) * LOG2_THETA);
  float ang = (float)t * freq;
  float c = cosf(ang), s = sinf(ang);
  float x0 = src[2 * i], x1 = src[2 * i + 1];
  float v0 = x0 * c - x1 * s;
  float v1 = x0 * s + x1 * c;
  int bh = b * 16 + h;
  int tile = t >> 6, cg = (t >> 4) & 3, frk = t & 15;
  int kg = 2 + (i >> 4), qd = (i >> 2) & 3, e = (2 * i) & 7;
  size_t off = (((size_t)(bh * 32 + tile) * 16) + cg * 4 + kg) * 512
             + (qd * 16 + frk) * 8 + e;
  *(unsigned*)(Kp + off) = pkbf(v0, v1);
}

__global__ __launch_bounds__(256) void k_cast_kvl(const float* __restrict__ ckv,
                                                  __bf16* __restrict__ kvl) {
  int idx = blockIdx.x * 256 + threadIdx.x;   // over BT*512
  int r = idx >> 9, c = idx & 511;
  kvl[idx] = (__bf16)ckv[(size_t)r * NKVAP_ + c];
}

// kv (BT,1024) f32 -> Kp nope dims (0..63) AND Vp, one read of kv
__global__ __launch_bounds__(256) void k_pack_kv(const float* __restrict__ kv,
                                                 __bf16* __restrict__ Kp,
                                                 __bf16* __restrict__ Vp) {
  __shared__ float tile[64][65];
  const int bh = blockIdx.x;
  const int b = bh >> 4, h = bh & 15;
  const int t0 = blockIdx.y * 64;
  const int tilei = t0 >> 6;
  const int tid = threadIdx.x;
  const int i0 = tid >> 4, d4 = (tid & 15) * 4;
  const int kg = d4 >> 5, qd = (d4 >> 3) & 3, e = d4 & 7;   // dim coords
#pragma unroll
  for (int p = 0; p < 4; ++p) {
    int i = i0 + p * 16;                                    // key within tile
    const float* src = kv + ((size_t)(b * T_ + t0 + i)) * 1024 + h * 64 + d4;
    float4 v = *(const float4*)src;
    tile[i][d4] = v.x; tile[i][d4 + 1] = v.y; tile[i][d4 + 2] = v.z; tile[i][d4 + 3] = v.w;
    union { __bf16 hh[4]; uint2 u; } o;
    o.hh[0] = (__bf16)v.x; o.hh[1] = (__bf16)v.y; o.hh[2] = (__bf16)v.z; o.hh[3] = (__bf16)v.w;
    const int cg = i >> 4, frk = i & 15;
    size_t koff = (((size_t)(bh * 32 + tilei) * 16) + cg * 4 + kg) * 512
                + (qd * 16 + frk) * 8 + e;
    *(uint2*)(Kp + koff) = o.u;
  }
  __syncthreads();
  const int dd = tid >> 2, tc0 = (tid & 3) * 16;
  __bf16 outv[16];
#pragma unroll
  for (int j = 0; j < 16; ++j) outv[j] = (__bf16)tile[tc0 + j][dd];
  const int g = dd >> 4, frv = dd & 15;
  const int ks = tc0 >> 5, qv = (tc0 >> 3) & 3;
  size_t voff = (((size_t)(bh * 32 + tilei) * 8) + g * 2 + ks) * 512
              + (qv * 16 + frv) * 8;
  *(bf16x8*)(Vp + voff) = *(bf16x8*)&outv[0];
  *(bf16x8*)(Vp + voff + 128) = *(bf16x8*)&outv[8];   // quad+1 -> +16*8 halfwords
}

// ---------------------------------------------------------------- attention
// R8-verified (k_attn ~68 us, VGPR 64, no spill): 8 waves (512 thr), waves
// 0-3 even K-tiles, waves 4-7 odd; fragment-packed K/V loaded directly from
// L2 (16+8 coalesced 1KB loads per tile); online-softmax partials merged via
// 18KB LDS + one barrier. K loads at loop head: R11's tail-rotation extended
// kr's live range across softmax/PV -> needed a 2nd 64-VGPR copy -> spill
// (WRITE_SIZE 624 GB). launch_bounds(512,4) = 128 VGPR cap.
__global__ __launch_bounds__(512, 4) void k_attn(const __bf16* __restrict__ qf,
                                                 const __bf16* __restrict__ Kp,
                                                 const __bf16* __restrict__ Vp,
                                                 __bf16* __restrict__ yc) {
  const int blk = blockIdx.x;          // 1024 = 32 qt * 32 bh
  const int bh = blk & 31;             // bh mod 8 == XCD -> per-XCD L2 locality
  const int qt = 31 - (blk >> 5);      // heavy tiles first
  const int b = bh >> 4, h = bh & 15;
  const int qbase = qt * 64;
  const int tid = threadIdx.x;
  const int lane = tid & 63, wave = tid >> 6;    // 0..7
  const int w4 = wave & 3, par = wave >> 2;      // q-row group, K-tile parity
  const int fr = lane & 15, quad = lane >> 4, fk8 = quad * 8;

  __shared__ __align__(16) f32x4 mrgO[4][64][4]; // 16 KB partial accO
  __shared__ float mrgML[4][64][2];              // 2 KB partial m,l

  const int qi = qbase + w4 * 16 + fr;           // this lane's q-row
  const __bf16* qb = qf + ((size_t)bh * T_ + qi) * HD_;
  bf16x8 aq[4];
#pragma unroll
  for (int g = 0; g < 4; ++g) aq[g] = *(const bf16x8*)(qb + g * 32 + fk8);

  const f32x4 fzero = {0.f, 0.f, 0.f, 0.f};
  f32x4 accO[4];
#pragma unroll
  for (int g = 0; g < 4; ++g) accO[g] = fzero;
  float m = -1e30f, l = 0.f;

  const __bf16* kb = Kp + (size_t)bh * 32 * 8192 + (size_t)lane * 8;
  const __bf16* vb = Vp + (size_t)bh * 32 * 4096 + (size_t)lane * 8;
  const int srcA = (quad & 1) * 32 + fr, srcB = srcA + 16;
  const int hi = quad >> 1;

  for (int s0 = par * 64; s0 <= qbase; s0 += 128) {
    const __bf16* kt = kb + (size_t)(s0 >> 6) * 8192;
    const __bf16* vt = vb + (size_t)(s0 >> 6) * 4096;

    // K fragments: 16 coalesced 1KB loads
    bf16x8 kr[4][4];
#pragma unroll
    for (int cg = 0; cg < 4; ++cg)
#pragma unroll
      for (int kg = 0; kg < 4; ++kg)
        kr[cg][kg] = *(const bf16x8*)(kt + (cg * 4 + kg) * 512);

    // S^T: rows = keys (quad*4+r), cols = q (fr)
    f32x4 accST[4];
#pragma unroll
    for (int cg = 0; cg < 4; ++cg) accST[cg] = fzero;
    __builtin_amdgcn_s_setprio(1);
#pragma unroll
    for (int cg = 0; cg < 4; ++cg) {
#pragma unroll
      for (int kg = 0; kg < 4; ++kg)
        accST[cg] = MFMA16(kr[cg][kg], aq[kg], accST[cg]);
    }
    __builtin_amdgcn_s_setprio(0);

    // V fragments issued now; latency hides under the softmax VALU phase
    bf16x8 vr[4][2];
#pragma unroll
    for (int g = 0; g < 4; ++g)
#pragma unroll
      for (int ks = 0; ks < 2; ++ks)
        vr[g][ks] = *(const bf16x8*)(vt + (g * 2 + ks) * 512);

    // row max (mask only on the diagonal tile; values pre-scaled via qf)
    float lmax = -1e30f;
    if (s0 == qbase) {
#pragma unroll
      for (int cg = 0; cg < 4; ++cg) {
#pragma unroll
        for (int r = 0; r < 4; ++r) {
          const int key = s0 + cg * 16 + quad * 4 + r;
          float v = accST[cg][r];
          v = (key <= qi) ? v : -1e30f;
          accST[cg][r] = v;
          lmax = fmaxf(lmax, v);
        }
      }
    } else {
#pragma unroll
      for (int cg = 0; cg < 4; ++cg) {
#pragma unroll
        for (int r = 0; r < 4; ++r) lmax = fmaxf(lmax, accST[cg][r]);
      }
    }
    lmax = fmaxf(lmax, __shfl_xor(lmax, 16, 64));
    lmax = fmaxf(lmax, __shfl_xor(lmax, 32, 64));

    // T13 defer-max: only rescale when the running max grew by > 8
    if (!__all(lmax <= m + 8.0f)) {
      const float mn = fmaxf(m, lmax);
      const float alpha = exp2f(m - mn);
      l *= alpha;
#pragma unroll
      for (int g = 0; g < 4; ++g)
#pragma unroll
        for (int r = 0; r < 4; ++r) accO[g][r] *= alpha;
      m = mn;
    }

    float lsum = 0.f;
    unsigned pk0[4], pk1[4];
#pragma unroll
    for (int cg = 0; cg < 4; ++cg) {
      float p0 = exp2f(accST[cg][0] - m);
      float p1 = exp2f(accST[cg][1] - m);
      float p2 = exp2f(accST[cg][2] - m);
      float p3 = exp2f(accST[cg][3] - m);
      lsum += (p0 + p1) + (p2 + p3);
      pk0[cg] = pkbf(p0, p1);
      pk1[cg] = pkbf(p2, p3);
    }
    lsum += __shfl_xor(lsum, 16, 64);
    lsum += __shfl_xor(lsum, 32, 64);
    l += lsum;

    // PV: B-operand (P) built from register shuffles
#pragma unroll
    for (int ks = 0; ks < 2; ++ks) {
      int a0 = __shfl((int)pk0[2 * ks], srcA, 64);
      int b0 = __shfl((int)pk0[2 * ks + 1], srcA, 64);
      int a1 = __shfl((int)pk1[2 * ks], srcA, 64);
      int b1 = __shfl((int)pk1[2 * ks + 1], srcA, 64);
      int a2 = __shfl((int)pk0[2 * ks], srcB, 64);
      int b2 = __shfl((int)pk0[2 * ks + 1], srcB, 64);
      int a3 = __shfl((int)pk1[2 * ks], srcB, 64);
      int b3 = __shfl((int)pk1[2 * ks + 1], srcB, 64);
      union { int i[4]; bf16x8 v; } pf;
      pf.i[0] = hi ? b0 : a0;
      pf.i[1] = hi ? b1 : a1;
      pf.i[2] = hi ? b2 : a2;
      pf.i[3] = hi ? b3 : a3;
      __builtin_amdgcn_s_setprio(1);
#pragma unroll
      for (int g = 0; g < 4; ++g)
        accO[g] = MFMA16(vr[g][ks], pf.v, accO[g]);
      __builtin_amdgcn_s_setprio(0);
    }
  }

  // split-K merge: odd-parity waves publish partials, even-parity merge+store
  if (par) {
#pragma unroll
    for (int g = 0; g < 4; ++g) mrgO[w4][lane][g] = accO[g];
    mrgML[w4][lane][0] = m;
    mrgML[w4][lane][1] = l;
  }
  __syncthreads();
  if (!par) {
    const float m1 = mrgML[w4][lane][0];
    const float l1 = mrgML[w4][lane][1];
    const float mn = fmaxf(m, m1);
    const float a0 = exp2f(m - mn), a1 = exp2f(m1 - mn);
    const float lt = l * a0 + l1 * a1;
    const float linv = 1.0f / lt;
    // epilogue: O^T -> yc[(b*T+qi)*1024 + h*64 + d], d = g*16 + quad*4 + r
    __bf16* yb = yc + ((size_t)(b * T_ + qi)) * 1024 + h * 64 + quad * 4;
#pragma unroll
    for (int g = 0; g < 4; ++g) {
      f32x4 o1 = mrgO[w4][lane][g];
      union { unsigned u[2]; uint2 v; } o;
      o.u[0] = pkbf((accO[g][0] * a0 + o1[0] * a1) * linv,
                    (accO[g][1] * a0 + o1[1] * a1) * linv);
      o.u[1] = pkbf((accO[g][2] * a0 + o1[2] * a1) * linv,
                    (accO[g][3] * a0 + o1[3] * a1) * linv);
      *(uint2*)(yb + g * 16) = o.v;
    }
  }
}

// ---------------------------------------------------------------- launch
extern "C" void kernel_launch(void* const* d_in, const int* in_sizes, int n_in,
                              void* d_out, int out_size, void* d_ws, size_t ws_size,
                              hipStream_t stream) {
  const float* x    = (const float*)d_in[0];
  const float* Wq   = (const float*)d_in[1];
  const float* Wkva = (const float*)d_in[2];
  const float* Wkvb = (const float*)d_in[3];
  const float* Wo   = (const float*)d_in[4];
  float* out = (float*)d_out;
  char* ws = (char*)d_ws;

  // workspace layout (bytes)
  size_t off = 0;
  __bf16* xb    = (__bf16*)(ws + off); off += (size_t)BT_ * C_ * 2;          // 16.78M
  __bf16* WqT   = (__bf16*)(ws + off); off += (size_t)2048 * 2048 * 2;       // 8.39M
  __bf16* WkvaT = (__bf16*)(ws + off); off += (size_t)NKVAP_ * 2048 * 2;     // 2.62M
  __bf16* WkvbT = (__bf16*)(ws + off); off += (size_t)1024 * 512 * 2;        // 1.05M
  __bf16* WoTc  = (__bf16*)(ws + off); off += (size_t)2048 * 1024 * 2;       // 4.19M
  float*  q     = (float*)(ws + off);  off += (size_t)BT_ * 2048 * 4;        // 33.55M
  float*  ckv   = (float*)(ws + off);  off += (size_t)BT_ * NKVAP_ * 4;      // 10.49M
  __bf16* kvl   = (__bf16*)(ws + off); off += (size_t)BT_ * 512 * 2;         // 4.19M
  float*  kv    = (float*)(ws + off);  off += (size_t)BT_ * 1024 * 4;        // 16.78M
  __bf16* qfb   = (__bf16*)(ws + off); off += (size_t)B_ * H_ * T_ * HD_ * 2;// 16.78M
  __bf16* yc    = (__bf16*)(ws + off); off += (size_t)BT_ * 1024 * 2;        // 8.39M
  // Kp (16.78M) and Vp (8.39M) alias q's 33.55M buffer: q is dead after
  // k_rope_q, and both are written strictly after k_rope_q in stream order.
  __bf16* Kp = (__bf16*)q;
  __bf16* Vp = (__bf16*)((char*)q + (size_t)B_ * H_ * T_ * HD_ * 2);

  // 1. casts / transposes
  k_cast_x<<<(BT_ * C_) / 256, 256, 0, stream>>>(x, xb, BT_ * C_);
  k_tcast<<<dim3(2048 / 32, 2048 / 32), 256, 0, stream>>>(Wq, WqT, 2048, 2048, 2048);
  k_tcast<<<dim3(2048 / 32, NKVAP_ / 32), 256, 0, stream>>>(Wkva, WkvaT, 2048, NKVA_, NKVAP_);
  k_tcast<<<dim3(512 / 32, 1024 / 32), 256, 0, stream>>>(Wkvb, WkvbT, 512, 1024, 1024);
  k_tcast_wo<<<dim3(1024 / 32, 2048 / 32), 256, 0, stream>>>(Wo, WoTc);

  // 2. projections
  k_gemm_bt<<<dim3(BT_ / 128, 2048 / 128), 256, 0, stream>>>(xb, WqT, q, BT_, 2048, 2048);
  k_gemm_bt<<<dim3(BT_ / 128, NKVAP_ / 128), 256, 0, stream>>>(xb, WkvaT, ckv, BT_, NKVAP_, 2048);

  // 3. rope + casts (q buffer dead after k_rope_q)
  k_rope_q<<<(B_ * H_ * T_ * HD_) / 256, 256, 0, stream>>>(q, qfb);
  k_cast_kvl<<<(BT_ * 512) / 256, 256, 0, stream>>>(ckv, kvl);

  // 4. kv up-projection, then pack Kp (nope+rope) and Vp
  k_gemm_bt<<<dim3(BT_ / 128, 1024 / 128), 256, 0, stream>>>(kvl, WkvbT, kv, BT_, 1024, 512);
  k_pack_kv<<<dim3(B_ * H_, T_ / 64), 256, 0, stream>>>(kv, Kp, Vp);
  k_rope_kf<<<(B_ * H_ * T_ * 32) / 256, 256, 0, stream>>>(ckv, Kp);

  // 5. attention (1024 blocks x 512 threads; split-K pairs of waves)
  k_attn<<<(T_ / 64) * B_ * H_, 512, 0, stream>>>(qfb, Kp, Vp, yc);

  // 6. output projection
  k_gemm_bt<<<dim3(BT_ / 128, 2048 / 128), 256, 0, stream>>>(yc, WoTc, out, BT_, 2048, 1024);
}

// Round 14
// 323.743 us; speedup vs baseline: 1.5122x; 1.0421x over previous
//
#include <hip/hip_runtime.h>
#include <hip/hip_bf16.h>
#include <math.h>

// Problem constants
#define B_ 2
#define T_ 2048
#define C_ 2048
#define H_ 16
#define HD_ 128
#define LORA_ 512
#define RD_ 64
#define ND_ 64
#define BT_ (B_*T_)            // 4096
#define NKVA_ 576              // LORA + RD
#define NKVAP_ 640             // padded to 128
#define LOG2_THETA 16.609640474436812f

typedef __bf16 bf16x8 __attribute__((ext_vector_type(8)));
typedef float  f32x4  __attribute__((ext_vector_type(4)));

#define MFMA16(a,b,c) __builtin_amdgcn_mfma_f32_16x16x32_bf16((a),(b),(c),0,0,0)

// global -> LDS direct 16B copy (lds dest must be wave-uniform base + lane*16)
__device__ static inline void load_lds16(const __bf16* g, __bf16* l) {
  auto* lp = (__attribute__((address_space(3))) char*)(uintptr_t)(l);
  auto* gp = (const __attribute__((address_space(1))) char*)(g);
  __builtin_amdgcn_global_load_lds(gp, lp, 16, 0, 0);
}

__device__ static inline unsigned pkbf(float a, float b) {
  union { __bf16 h[2]; unsigned u; } v;
  v.h[0] = (__bf16)a; v.h[1] = (__bf16)b;
  return v.u;
}

// ---------------------------------------------------------------- casts
__global__ __launch_bounds__(256) void k_cast_x(const float* __restrict__ x,
                                                __bf16* __restrict__ xb, int n) {
  int idx = blockIdx.x * 256 + threadIdx.x;
  if (idx < n) xb[idx] = (__bf16)x[idx];
}

// dst[n][k] = src[k][n]; src (K,N) f32, dst (NP,K) bf16, zero-fill n in [N,NP)
__global__ __launch_bounds__(256) void k_tcast(const float* __restrict__ src,
                                               __bf16* __restrict__ dst,
                                               int K, int N, int NP) {
  __shared__ float tile[32][33];
  int k0 = blockIdx.x * 32;
  int n0 = blockIdx.y * 32;
  int tx = threadIdx.x & 31, ty = threadIdx.x >> 5;
  for (int i = ty; i < 32; i += 8) {
    int n = n0 + tx;
    tile[i][tx] = (n < N) ? src[(size_t)(k0 + i) * N + n] : 0.0f;
  }
  __syncthreads();
  for (int i = ty; i < 32; i += 8) {
    dst[(size_t)(n0 + i) * K + k0 + tx] = (__bf16)tile[tx][i];
  }
}

// dst[n][kc] = Wo[(kc>>6)*128 + (kc&63)][n]; dst (2048,1024) bf16
__global__ __launch_bounds__(256) void k_tcast_wo(const float* __restrict__ Wo,
                                                  __bf16* __restrict__ dst) {
  __shared__ float tile[32][33];
  int kc0 = blockIdx.x * 32;
  int n0  = blockIdx.y * 32;
  int rbase = (kc0 >> 6) * 128 + (kc0 & 63);
  int tx = threadIdx.x & 31, ty = threadIdx.x >> 5;
  for (int i = ty; i < 32; i += 8)
    tile[i][tx] = Wo[(size_t)(rbase + i) * C_ + n0 + tx];
  __syncthreads();
  for (int i = ty; i < 32; i += 8)
    dst[(size_t)(n0 + i) * 1024 + kc0 + tx] = (__bf16)tile[tx][i];
}

// ---------------------------------------------------------------- GEMM
// R8-verified: 128x128 tile, BK=32, 4 waves, 256 threads, double-buffered
// global_load_lds staging. Used for Wkvb and Wo.
__global__ __launch_bounds__(256) void k_gemm_bt(const __bf16* __restrict__ A,
                                                 const __bf16* __restrict__ B,
                                                 float* __restrict__ C,
                                                 int M, int N, int K) {
  __shared__ __align__(16) __bf16 As[2][128 * 32];
  __shared__ __align__(16) __bf16 Bs[2][128 * 32];
  const int tid  = threadIdx.x;
  const int lane = tid & 63;
  const int wave = tid >> 6;
  const int bm = blockIdx.x, bn = blockIdx.y;
  const int r0 = tid >> 2;
  const int c8 = (tid & 3) * 8;
  const __bf16* Ag = A + (size_t)(bm * 128 + r0) * K + c8;
  const __bf16* Bg = B + (size_t)(bn * 128 + r0) * K + c8;
  const int wr = (wave >> 1) * 64, wc = (wave & 1) * 64;
  const int fr = lane & 15, fk = (lane >> 4) * 8;
  const f32x4 fzero = {0.f, 0.f, 0.f, 0.f};
  f32x4 acc[4][4];
#pragma unroll
  for (int i = 0; i < 4; ++i)
#pragma unroll
    for (int j = 0; j < 4; ++j) acc[i][j] = fzero;

  // stage tile 0 into buf 0
  load_lds16(Ag,                  &As[0][tid * 8]);
  load_lds16(Ag + (size_t)64 * K, &As[0][tid * 8 + 2048]);
  load_lds16(Bg,                  &Bs[0][tid * 8]);
  load_lds16(Bg + (size_t)64 * K, &Bs[0][tid * 8 + 2048]);

  int buf = 0;
  for (int k0 = 0; k0 < K; k0 += 32) {
    __syncthreads();   // drains own vmcnt -> buf's staging complete for all
    if (k0 + 32 < K) {
      const int nb = buf ^ 1;
      load_lds16(Ag + k0 + 32,                  &As[nb][tid * 8]);
      load_lds16(Ag + (size_t)64 * K + k0 + 32, &As[nb][tid * 8 + 2048]);
      load_lds16(Bg + k0 + 32,                  &Bs[nb][tid * 8]);
      load_lds16(Bg + (size_t)64 * K + k0 + 32, &Bs[nb][tid * 8 + 2048]);
    }
    bf16x8 af[4], bfg[4];
#pragma unroll
    for (int i = 0; i < 4; ++i) af[i]  = *(const bf16x8*)&As[buf][(wr + i * 16 + fr) * 32 + fk];
#pragma unroll
    for (int j = 0; j < 4; ++j) bfg[j] = *(const bf16x8*)&Bs[buf][(wc + j * 16 + fr) * 32 + fk];
#pragma unroll
    for (int i = 0; i < 4; ++i)
#pragma unroll
      for (int j = 0; j < 4; ++j)
        acc[i][j] = MFMA16(af[i], bfg[j], acc[i][j]);
    buf ^= 1;
  }
  const int rbase = (lane >> 4) * 4;
  float* Cb = C + (size_t)(bm * 128 + wr + rbase) * N + bn * 128 + wc + fr;
#pragma unroll
  for (int i = 0; i < 4; ++i)
#pragma unroll
    for (int j = 0; j < 4; ++j)
#pragma unroll
      for (int r = 0; r < 4; ++r)
        Cb[(size_t)(i * 16 + r) * N + j * 16] = acc[i][j][r];
}

// ---------------------------------------------------------------- merged Wq+Wkva GEMM
// R13: the Wq and Wkva GEMMs are INDEPENDENT (both read only xb) but
// serialized in-stream; Wkva alone is 160 blocks = 0.6/CU. One dispatch over
// N=2688 (WqT||WkvaT contiguous in workspace): grid 32x21 = 672 blocks.
// PLAIN f32 epilogue (branch on bn only for dest/stride) -- R8's regression
// came from the trig-fused epilogue, not the merge itself. K-loop identical
// to k_gemm_bt -> bit-identical outputs to the two separate GEMMs.
__global__ __launch_bounds__(256) void k_gemm_qkva(const __bf16* __restrict__ A,
                                                   const __bf16* __restrict__ Bq,
                                                   float* __restrict__ q,
                                                   float* __restrict__ ckv) {
  const int K = 2048;
  __shared__ __align__(16) __bf16 As[2][128 * 32];
  __shared__ __align__(16) __bf16 Bs[2][128 * 32];
  const int tid  = threadIdx.x;
  const int lane = tid & 63;
  const int wave = tid >> 6;
  const int bm = blockIdx.x, bn = blockIdx.y;
  const int r0 = tid >> 2;
  const int c8 = (tid & 3) * 8;
  const __bf16* Ag = A  + (size_t)(bm * 128 + r0) * K + c8;
  const __bf16* Bg = Bq + (size_t)(bn * 128 + r0) * K + c8;
  const int wr = (wave >> 1) * 64, wc = (wave & 1) * 64;
  const int fr = lane & 15, fk = (lane >> 4) * 8;
  const f32x4 fzero = {0.f, 0.f, 0.f, 0.f};
  f32x4 acc[4][4];
#pragma unroll
  for (int i = 0; i < 4; ++i)
#pragma unroll
    for (int j = 0; j < 4; ++j) acc[i][j] = fzero;

  load_lds16(Ag,                  &As[0][tid * 8]);
  load_lds16(Ag + (size_t)64 * K, &As[0][tid * 8 + 2048]);
  load_lds16(Bg,                  &Bs[0][tid * 8]);
  load_lds16(Bg + (size_t)64 * K, &Bs[0][tid * 8 + 2048]);

  int buf = 0;
  for (int k0 = 0; k0 < K; k0 += 32) {
    __syncthreads();
    if (k0 + 32 < K) {
      const int nb = buf ^ 1;
      load_lds16(Ag + k0 + 32,                  &As[nb][tid * 8]);
      load_lds16(Ag + (size_t)64 * K + k0 + 32, &As[nb][tid * 8 + 2048]);
      load_lds16(Bg + k0 + 32,                  &Bs[nb][tid * 8]);
      load_lds16(Bg + (size_t)64 * K + k0 + 32, &Bs[nb][tid * 8 + 2048]);
    }
    bf16x8 af[4], bfg[4];
#pragma unroll
    for (int i = 0; i < 4; ++i) af[i]  = *(const bf16x8*)&As[buf][(wr + i * 16 + fr) * 32 + fk];
#pragma unroll
    for (int j = 0; j < 4; ++j) bfg[j] = *(const bf16x8*)&Bs[buf][(wc + j * 16 + fr) * 32 + fk];
#pragma unroll
    for (int i = 0; i < 4; ++i)
#pragma unroll
      for (int j = 0; j < 4; ++j)
        acc[i][j] = MFMA16(af[i], bfg[j], acc[i][j]);
    buf ^= 1;
  }
  const int rbase = (lane >> 4) * 4;
  float* Cb;
  int stride;
  if (bn < 16) { Cb = q   + (size_t)(bm * 128 + wr + rbase) * 2048 + bn * 128 + wc + fr;        stride = 2048; }
  else         { Cb = ckv + (size_t)(bm * 128 + wr + rbase) * NKVAP_ + (bn - 16) * 128 + wc + fr; stride = NKVAP_; }
#pragma unroll
  for (int i = 0; i < 4; ++i)
#pragma unroll
    for (int j = 0; j < 4; ++j)
#pragma unroll
      for (int r = 0; r < 4; ++r)
        Cb[(size_t)(i * 16 + r) * stride + j * 16] = acc[i][j][r];
}

// ---------------------------------------------------------------- rope
// q (BT,2048) f32 -> qf [b][h][t][128] bf16, rope on d in [64,128)
// NOTE: q is pre-scaled by log2(e)/sqrt(HD) here so the attention kernel can
// feed MFMA results straight into exp2f with no per-element multiply.
__global__ __launch_bounds__(256) void k_rope_q(const float* __restrict__ q,
                                                __bf16* __restrict__ qf) {
  const float scale2 = 1.4426950408889634f / 11.313708498984760f; // log2e/sqrt(128)
  int idx = blockIdx.x * 256 + threadIdx.x;   // over B*H*T*HD = 8388608
  int d  = idx & 127;
  int t  = (idx >> 7) & 2047;
  int bh = idx >> 18;
  int h  = bh & 15, b = bh >> 4;
  const float* qrow = q + ((size_t)(b * T_ + t)) * 2048 + h * 128;
  float v;
  if (d < 64) {
    v = qrow[d];
  } else {
    int i = (d - 64) >> 1;
    float freq = exp2f(-((float)(2 * i) / 64.0f) * LOG2_THETA);
    float ang = (float)t * freq;
    float c = cosf(ang), s = sinf(ang);
    float x0 = qrow[64 + 2 * i], x1 = qrow[64 + 2 * i + 1];
    v = (d & 1) ? (x0 * s + x1 * c) : (x0 * c - x1 * s);
  }
  qf[idx] = (__bf16)(v * scale2);
}

// Fragment-packed K layout (consumed by the no-LDS attention kernel):
//   Kp[bh][tile][cg][kg][lane][8 bf16], tile = key>>6, cg = (key>>4)&3,
//   fr = key&15, kg = dim>>5, quad = (dim>>3)&3, e = dim&7, lane = quad*16+fr.
// Vp[bh][tile][g][ks][lane][8]: dim row = g*16+fr, key col = ks*32+quad*8+e.

// ckv (BT,640) f32 cols [512,576) -> Kp rope dims (64..127), dup per h
__global__ __launch_bounds__(256) void k_rope_kf(const float* __restrict__ ckv,
                                                 __bf16* __restrict__ Kp) {
  int idx = blockIdx.x * 256 + threadIdx.x;   // over B*H*T*32 = 2097152 (pairs)
  int i = idx & 31;            // rope pair index: dims 64+2i, 64+2i+1
  int t = (idx >> 5) & 2047;
  int h = (idx >> 16) & 15;
  int b = idx >> 20;
  const float* src = ckv + ((size_t)(b * T_ + t)) * NKVAP_ + 512;
  float freq = exp2f(-((float)(2 * i) / 64.0f) * LOG2_THETA);
  float ang = (float)t * freq;
  float c = cosf(ang), s = sinf(ang);
  float x0 = src[2 * i], x1 = src[2 * i + 1];
  float v0 = x0 * c - x1 * s;
  float v1 = x0 * s + x1 * c;
  int bh = b * 16 + h;
  int tile = t >> 6, cg = (t >> 4) & 3, frk = t & 15;
  int kg = 2 + (i >> 4), qd = (i >> 2) & 3, e = (2 * i) & 7;
  size_t off = (((size_t)(bh * 32 + tile) * 16) + cg * 4 + kg) * 512
             + (qd * 16 + frk) * 8 + e;
  *(unsigned*)(Kp + off) = pkbf(v0, v1);
}

__global__ __launch_bounds__(256) void k_cast_kvl(const float* __restrict__ ckv,
                                                  __bf16* __restrict__ kvl) {
  int idx = blockIdx.x * 256 + threadIdx.x;   // over BT*512
  int r = idx >> 9, c = idx & 511;
  kvl[idx] = (__bf16)ckv[(size_t)r * NKVAP_ + c];
}

// kv (BT,1024) f32 -> Kp nope dims (0..63) AND Vp, one read of kv
__global__ __launch_bounds__(256) void k_pack_kv(const float* __restrict__ kv,
                                                 __bf16* __restrict__ Kp,
                                                 __bf16* __restrict__ Vp) {
  __shared__ float tile[64][65];
  const int bh = blockIdx.x;
  const int b = bh >> 4, h = bh & 15;
  const int t0 = blockIdx.y * 64;
  const int tilei = t0 >> 6;
  const int tid = threadIdx.x;
  const int i0 = tid >> 4, d4 = (tid & 15) * 4;
  const int kg = d4 >> 5, qd = (d4 >> 3) & 3, e = d4 & 7;   // dim coords
#pragma unroll
  for (int p = 0; p < 4; ++p) {
    int i = i0 + p * 16;                                    // key within tile
    const float* src = kv + ((size_t)(b * T_ + t0 + i)) * 1024 + h * 64 + d4;
    float4 v = *(const float4*)src;
    tile[i][d4] = v.x; tile[i][d4 + 1] = v.y; tile[i][d4 + 2] = v.z; tile[i][d4 + 3] = v.w;
    union { __bf16 hh[4]; uint2 u; } o;
    o.hh[0] = (__bf16)v.x; o.hh[1] = (__bf16)v.y; o.hh[2] = (__bf16)v.z; o.hh[3] = (__bf16)v.w;
    const int cg = i >> 4, frk = i & 15;
    size_t koff = (((size_t)(bh * 32 + tilei) * 16) + cg * 4 + kg) * 512
                + (qd * 16 + frk) * 8 + e;
    *(uint2*)(Kp + koff) = o.u;
  }
  __syncthreads();
  const int dd = tid >> 2, tc0 = (tid & 3) * 16;
  __bf16 outv[16];
#pragma unroll
  for (int j = 0; j < 16; ++j) outv[j] = (__bf16)tile[tc0 + j][dd];
  const int g = dd >> 4, frv = dd & 15;
  const int ks = tc0 >> 5, qv = (tc0 >> 3) & 3;
  size_t voff = (((size_t)(bh * 32 + tilei) * 8) + g * 2 + ks) * 512
              + (qv * 16 + frv) * 8;
  *(bf16x8*)(Vp + voff) = *(bf16x8*)&outv[0];
  *(bf16x8*)(Vp + voff + 128) = *(bf16x8*)&outv[8];   // quad+1 -> +16*8 halfwords
}

// ---------------------------------------------------------------- attention
// R13: load-balanced. R8's counters: occupancy 37% time-averaged despite
// 4-blocks/CU resources -- causal skew (work ~ qt+1, 32:1) leaves stragglers
// at low residency. Fix: each block processes TWO q-tiles, qt=p and qt=31-p
// (p = blk>>5), so every block does equal work (~17 tile-iters). Grid 512.
// Each pass is the verified R7 split-K loop (registers reused sequentially,
// no live-range growth -- unlike R11's spilling prefetch); one extra barrier
// between passes protects merge-LDS reuse. Bonus: light tile's K/V is a
// prefix of heavy tile's -> same-block L2/L1 reuse. Math per tile unchanged.
__global__ __launch_bounds__(512, 4) void k_attn(const __bf16* __restrict__ qf,
                                                 const __bf16* __restrict__ Kp,
                                                 const __bf16* __restrict__ Vp,
                                                 __bf16* __restrict__ yc) {
  const int blk = blockIdx.x;          // 512 = 16 pair * 32 bh
  const int bh = blk & 31;             // bh mod 8 == XCD -> per-XCD L2 locality
  const int p  = blk >> 5;             // tile pair: qt = p and 31-p
  const int b = bh >> 4, h = bh & 15;
  const int tid = threadIdx.x;
  const int lane = tid & 63, wave = tid >> 6;    // 0..7
  const int w4 = wave & 3, par = wave >> 2;      // q-row group, K-tile parity
  const int fr = lane & 15, quad = lane >> 4, fk8 = quad * 8;

  __shared__ __align__(16) f32x4 mrgO[4][64][4]; // 16 KB partial accO
  __shared__ float mrgML[4][64][2];              // 2 KB partial m,l

  const __bf16* kb = Kp + (size_t)bh * 32 * 8192 + (size_t)lane * 8;
  const __bf16* vb = Vp + (size_t)bh * 32 * 4096 + (size_t)lane * 8;
  const int srcA = (quad & 1) * 32 + fr, srcB = srcA + 16;
  const int hi = quad >> 1;
  const f32x4 fzero = {0.f, 0.f, 0.f, 0.f};

  auto process = [&](int qt) {
    const int qbase = qt * 64;
    const int qi = qbase + w4 * 16 + fr;         // this lane's q-row
    const __bf16* qb = qf + ((size_t)bh * T_ + qi) * HD_;
    bf16x8 aq[4];
#pragma unroll
    for (int g = 0; g < 4; ++g) aq[g] = *(const bf16x8*)(qb + g * 32 + fk8);

    f32x4 accO[4];
#pragma unroll
    for (int g = 0; g < 4; ++g) accO[g] = fzero;
    float m = -1e30f, l = 0.f;

    for (int s0 = par * 64; s0 <= qbase; s0 += 128) {
      const __bf16* kt = kb + (size_t)(s0 >> 6) * 8192;
      const __bf16* vt = vb + (size_t)(s0 >> 6) * 4096;

      // K fragments: 16 coalesced 1KB loads
      bf16x8 kr[4][4];
#pragma unroll
      for (int cg = 0; cg < 4; ++cg)
#pragma unroll
        for (int kg = 0; kg < 4; ++kg)
          kr[cg][kg] = *(const bf16x8*)(kt + (cg * 4 + kg) * 512);

      // S^T: rows = keys (quad*4+r), cols = q (fr)
      f32x4 accST[4];
#pragma unroll
      for (int cg = 0; cg < 4; ++cg) accST[cg] = fzero;
      __builtin_amdgcn_s_setprio(1);
#pragma unroll
      for (int cg = 0; cg < 4; ++cg) {
#pragma unroll
        for (int kg = 0; kg < 4; ++kg)
          accST[cg] = MFMA16(kr[cg][kg], aq[kg], accST[cg]);
      }
      __builtin_amdgcn_s_setprio(0);

      // V fragments issued now; latency hides under the softmax VALU phase
      bf16x8 vr[4][2];
#pragma unroll
      for (int g = 0; g < 4; ++g)
#pragma unroll
        for (int ks = 0; ks < 2; ++ks)
          vr[g][ks] = *(const bf16x8*)(vt + (g * 2 + ks) * 512);

      // row max (mask only on the diagonal tile; values pre-scaled via qf)
      float lmax = -1e30f;
      if (s0 == qbase) {
#pragma unroll
        for (int cg = 0; cg < 4; ++cg) {
#pragma unroll
          for (int r = 0; r < 4; ++r) {
            const int key = s0 + cg * 16 + quad * 4 + r;
            float v = accST[cg][r];
            v = (key <= qi) ? v : -1e30f;
            accST[cg][r] = v;
            lmax = fmaxf(lmax, v);
          }
        }
      } else {
#pragma unroll
        for (int cg = 0; cg < 4; ++cg) {
#pragma unroll
          for (int r = 0; r < 4; ++r) lmax = fmaxf(lmax, accST[cg][r]);
        }
      }
      lmax = fmaxf(lmax, __shfl_xor(lmax, 16, 64));
      lmax = fmaxf(lmax, __shfl_xor(lmax, 32, 64));

      // T13 defer-max: only rescale when the running max grew by > 8
      if (!__all(lmax <= m + 8.0f)) {
        const float mn = fmaxf(m, lmax);
        const float alpha = exp2f(m - mn);
        l *= alpha;
#pragma unroll
        for (int g = 0; g < 4; ++g)
#pragma unroll
          for (int r = 0; r < 4; ++r) accO[g][r] *= alpha;
        m = mn;
      }

      float lsum = 0.f;
      unsigned pk0[4], pk1[4];
#pragma unroll
      for (int cg = 0; cg < 4; ++cg) {
        float p0 = exp2f(accST[cg][0] - m);
        float p1 = exp2f(accST[cg][1] - m);
        float p2 = exp2f(accST[cg][2] - m);
        float p3 = exp2f(accST[cg][3] - m);
        lsum += (p0 + p1) + (p2 + p3);
        pk0[cg] = pkbf(p0, p1);
        pk1[cg] = pkbf(p2, p3);
      }
      lsum += __shfl_xor(lsum, 16, 64);
      lsum += __shfl_xor(lsum, 32, 64);
      l += lsum;

      // PV: B-operand (P) built from register shuffles
#pragma unroll
      for (int ks = 0; ks < 2; ++ks) {
        int a0 = __shfl((int)pk0[2 * ks], srcA, 64);
        int b0 = __shfl((int)pk0[2 * ks + 1], srcA, 64);
        int a1 = __shfl((int)pk1[2 * ks], srcA, 64);
        int b1 = __shfl((int)pk1[2 * ks + 1], srcA, 64);
        int a2 = __shfl((int)pk0[2 * ks], srcB, 64);
        int b2 = __shfl((int)pk0[2 * ks + 1], srcB, 64);
        int a3 = __shfl((int)pk1[2 * ks], srcB, 64);
        int b3 = __shfl((int)pk1[2 * ks + 1], srcB, 64);
        union { int i[4]; bf16x8 v; } pf;
        pf.i[0] = hi ? b0 : a0;
        pf.i[1] = hi ? b1 : a1;
        pf.i[2] = hi ? b2 : a2;
        pf.i[3] = hi ? b3 : a3;
        __builtin_amdgcn_s_setprio(1);
#pragma unroll
        for (int g = 0; g < 4; ++g)
          accO[g] = MFMA16(vr[g][ks], pf.v, accO[g]);
        __builtin_amdgcn_s_setprio(0);
      }
    }

    // split-K merge: odd-parity publish partials, even-parity merge+store
    if (par) {
#pragma unroll
      for (int g = 0; g < 4; ++g) mrgO[w4][lane][g] = accO[g];
      mrgML[w4][lane][0] = m;
      mrgML[w4][lane][1] = l;
    }
    __syncthreads();
    if (!par) {
      const float m1 = mrgML[w4][lane][0];
      const float l1 = mrgML[w4][lane][1];
      const float mn = fmaxf(m, m1);
      const float a0 = exp2f(m - mn), a1 = exp2f(m1 - mn);
      const float lt = l * a0 + l1 * a1;
      const float linv = 1.0f / lt;
      // epilogue: O^T -> yc[(b*T+qi)*1024 + h*64 + d], d = g*16+quad*4+r
      __bf16* yb = yc + ((size_t)(b * T_ + qi)) * 1024 + h * 64 + quad * 4;
#pragma unroll
      for (int g = 0; g < 4; ++g) {
        f32x4 o1 = mrgO[w4][lane][g];
        union { unsigned u[2]; uint2 v; } o;
        o.u[0] = pkbf((accO[g][0] * a0 + o1[0] * a1) * linv,
                      (accO[g][1] * a0 + o1[1] * a1) * linv);
        o.u[1] = pkbf((accO[g][2] * a0 + o1[2] * a1) * linv,
                      (accO[g][3] * a0 + o1[3] * a1) * linv);
        *(uint2*)(yb + g * 16) = o.v;
      }
    }
  };

  process(p);
  __syncthreads();      // protect merge-LDS reuse between the two passes
  process(31 - p);
}

// ---------------------------------------------------------------- launch
extern "C" void kernel_launch(void* const* d_in, const int* in_sizes, int n_in,
                              void* d_out, int out_size, void* d_ws, size_t ws_size,
                              hipStream_t stream) {
  const float* x    = (const float*)d_in[0];
  const float* Wq   = (const float*)d_in[1];
  const float* Wkva = (const float*)d_in[2];
  const float* Wkvb = (const float*)d_in[3];
  const float* Wo   = (const float*)d_in[4];
  float* out = (float*)d_out;
  char* ws = (char*)d_ws;

  // workspace layout (bytes)
  size_t off = 0;
  __bf16* xb    = (__bf16*)(ws + off); off += (size_t)BT_ * C_ * 2;          // 16.78M
  __bf16* WqT   = (__bf16*)(ws + off); off += (size_t)2048 * 2048 * 2;       // 8.39M
  __bf16* WkvaT = (__bf16*)(ws + off); off += (size_t)NKVAP_ * 2048 * 2;     // 2.62M (contiguous after WqT -> combined B, 2688 rows)
  __bf16* WkvbT = (__bf16*)(ws + off); off += (size_t)1024 * 512 * 2;        // 1.05M
  __bf16* WoTc  = (__bf16*)(ws + off); off += (size_t)2048 * 1024 * 2;       // 4.19M
  float*  q     = (float*)(ws + off);  off += (size_t)BT_ * 2048 * 4;        // 33.55M
  float*  ckv   = (float*)(ws + off);  off += (size_t)BT_ * NKVAP_ * 4;      // 10.49M
  __bf16* kvl   = (__bf16*)(ws + off); off += (size_t)BT_ * 512 * 2;         // 4.19M
  float*  kv    = (float*)(ws + off);  off += (size_t)BT_ * 1024 * 4;        // 16.78M
  __bf16* qfb   = (__bf16*)(ws + off); off += (size_t)B_ * H_ * T_ * HD_ * 2;// 16.78M
  __bf16* yc    = (__bf16*)(ws + off); off += (size_t)BT_ * 1024 * 2;        // 8.39M
  // Kp (16.78M) and Vp (8.39M) alias q's 33.55M buffer: q is dead after
  // k_rope_q, and both are written strictly after k_rope_q in stream order.
  __bf16* Kp = (__bf16*)q;
  __bf16* Vp = (__bf16*)((char*)q + (size_t)B_ * H_ * T_ * HD_ * 2);

  // 1. casts / transposes
  k_cast_x<<<(BT_ * C_) / 256, 256, 0, stream>>>(x, xb, BT_ * C_);
  k_tcast<<<dim3(2048 / 32, 2048 / 32), 256, 0, stream>>>(Wq, WqT, 2048, 2048, 2048);
  k_tcast<<<dim3(2048 / 32, NKVAP_ / 32), 256, 0, stream>>>(Wkva, WkvaT, 2048, NKVA_, NKVAP_);
  k_tcast<<<dim3(512 / 32, 1024 / 32), 256, 0, stream>>>(Wkvb, WkvbT, 512, 1024, 1024);
  k_tcast_wo<<<dim3(1024 / 32, 2048 / 32), 256, 0, stream>>>(Wo, WoTc);

  // 2. merged Wq+Wkva projection (independent GEMMs, one dispatch, N=2688)
  k_gemm_qkva<<<dim3(BT_ / 128, 2688 / 128), 256, 0, stream>>>(xb, WqT, q, ckv);

  // 3. rope + casts (q buffer dead after k_rope_q)
  k_rope_q<<<(B_ * H_ * T_ * HD_) / 256, 256, 0, stream>>>(q, qfb);
  k_cast_kvl<<<(BT_ * 512) / 256, 256, 0, stream>>>(ckv, kvl);

  // 4. kv up-projection, then pack Kp (nope+rope) and Vp
  k_gemm_bt<<<dim3(BT_ / 128, 1024 / 128), 256, 0, stream>>>(kvl, WkvbT, kv, BT_, 1024, 512);
  k_pack_kv<<<dim3(B_ * H_, T_ / 64), 256, 0, stream>>>(kv, Kp, Vp);
  k_rope_kf<<<(B_ * H_ * T_ * 32) / 256, 256, 0, stream>>>(ckv, Kp);

  // 5. attention (512 blocks x 512 threads; each block does qt=p and 31-p)
  k_attn<<<(T_ / 128) * B_ * H_, 512, 0, stream>>>(qfb, Kp, Vp, yc);

  // 6. output projection
  k_gemm_bt<<<dim3(BT_ / 128, 2048 / 128), 256, 0, stream>>>(yc, WoTc, out, BT_, 2048, 1024);
}

// Round 18
// 291.463 us; speedup vs baseline: 1.6797x; 1.1108x over previous
//
#include <hip/hip_runtime.h>
#include <hip/hip_bf16.h>
#include <math.h>

// Problem constants
#define B_ 2
#define T_ 2048
#define C_ 2048
#define H_ 16
#define HD_ 128
#define LORA_ 512
#define RD_ 64
#define ND_ 64
#define BT_ (B_*T_)            // 4096
#define NKVA_ 576              // LORA + RD
#define NKVAP_ 640             // padded to 128
#define LOG2_THETA 16.609640474436812f

typedef __bf16 bf16x8 __attribute__((ext_vector_type(8)));
typedef float  f32x4  __attribute__((ext_vector_type(4)));

#define MFMA16(a,b,c) __builtin_amdgcn_mfma_f32_16x16x32_bf16((a),(b),(c),0,0,0)

// global -> LDS direct 16B copy (lds dest must be wave-uniform base + lane*16)
__device__ static inline void load_lds16(const __bf16* g, __bf16* l) {
  auto* lp = (__attribute__((address_space(3))) char*)(uintptr_t)(l);
  auto* gp = (const __attribute__((address_space(1))) char*)(g);
  __builtin_amdgcn_global_load_lds(gp, lp, 16, 0, 0);
}

__device__ static inline unsigned pkbf(float a, float b) {
  union { __bf16 h[2]; unsigned u; } v;
  v.h[0] = (__bf16)a; v.h[1] = (__bf16)b;
  return v.u;
}

// ---------------------------------------------------------------- fused prologue
// R14: the 5 prologue ops (cast_x + 4 weight transposes) are independent;
// one block-partitioned dispatch removes 4 launch gaps and overlaps their
// tails. cast_x vectorized x8 (G13). Per-element math identical.
// Partition: 4096 (cast_x) + 4096 (Wq) + 1280 (Wkva) + 512 (Wkvb) + 2048 (Wo)
__global__ __launch_bounds__(256) void k_prep(const float* __restrict__ x,
                                              const float* __restrict__ Wq,
                                              const float* __restrict__ Wkva,
                                              const float* __restrict__ Wkvb,
                                              const float* __restrict__ Wo,
                                              __bf16* __restrict__ xb,
                                              __bf16* __restrict__ WqT,
                                              __bf16* __restrict__ WkvaT,
                                              __bf16* __restrict__ WkvbT,
                                              __bf16* __restrict__ WoTc) {
  __shared__ float tile[32][33];
  const int id = blockIdx.x;
  const int tid = threadIdx.x;
  if (id < 4096) {
    // cast_x, 8 elems/thread over BT_*C_ = 8388608
    const int idx = id * 256 + tid;
    const float* xp = x + (size_t)idx * 8;
    float4 a = *(const float4*)xp, bb = *(const float4*)(xp + 4);
    union { __bf16 h[8]; bf16x8 v; } o;
    o.h[0] = (__bf16)a.x;  o.h[1] = (__bf16)a.y;
    o.h[2] = (__bf16)a.z;  o.h[3] = (__bf16)a.w;
    o.h[4] = (__bf16)bb.x; o.h[5] = (__bf16)bb.y;
    o.h[6] = (__bf16)bb.z; o.h[7] = (__bf16)bb.w;
    *(bf16x8*)(xb + (size_t)idx * 8) = o.v;
    return;
  }
  const int tx = tid & 31, ty = tid >> 5;
  if (id < 9984) {
    // k_tcast: dst[n][k] = src[k][n], zero-fill n in [N,NP)
    const float* src; __bf16* dst; int K, N, bx, by;
    if (id < 8192)      { src = Wq;   dst = WqT;   K = 2048; N = 2048; int l = id - 4096; bx = l & 63; by = l >> 6; }
    else if (id < 9472) { src = Wkva; dst = WkvaT; K = 2048; N = NKVA_; int l = id - 8192; bx = l & 63; by = l >> 6; }
    else                { src = Wkvb; dst = WkvbT; K = 512;  N = 1024; int l = id - 9472; bx = l & 15; by = l >> 4; }
    const int k0 = bx * 32, n0 = by * 32;
    for (int i = ty; i < 32; i += 8) {
      int n = n0 + tx;
      tile[i][tx] = (n < N) ? src[(size_t)(k0 + i) * N + n] : 0.0f;
    }
    __syncthreads();
    for (int i = ty; i < 32; i += 8)
      dst[(size_t)(n0 + i) * K + k0 + tx] = (__bf16)tile[tx][i];
    return;
  }
  {
    // k_tcast_wo: dst[n][kc] = Wo[(kc>>6)*128 + (kc&63)][n]
    const int l = id - 9984;
    const int kc0 = (l & 31) * 32;
    const int n0  = (l >> 5) * 32;
    const int rbase = (kc0 >> 6) * 128 + (kc0 & 63);
    for (int i = ty; i < 32; i += 8)
      tile[i][tx] = Wo[(size_t)(rbase + i) * C_ + n0 + tx];
    __syncthreads();
    for (int i = ty; i < 32; i += 8)
      WoTc[(size_t)(n0 + i) * 1024 + kc0 + tx] = (__bf16)tile[tx][i];
  }
}

// ---------------------------------------------------------------- GEMM
// R8-verified: 128x128 tile, BK=32, 4 waves, 256 threads, double-buffered
// global_load_lds staging. Used for Wkvb and Wo.
__global__ __launch_bounds__(256) void k_gemm_bt(const __bf16* __restrict__ A,
                                                 const __bf16* __restrict__ B,
                                                 float* __restrict__ C,
                                                 int M, int N, int K) {
  __shared__ __align__(16) __bf16 As[2][128 * 32];
  __shared__ __align__(16) __bf16 Bs[2][128 * 32];
  const int tid  = threadIdx.x;
  const int lane = tid & 63;
  const int wave = tid >> 6;
  const int bm = blockIdx.x, bn = blockIdx.y;
  const int r0 = tid >> 2;
  const int c8 = (tid & 3) * 8;
  const __bf16* Ag = A + (size_t)(bm * 128 + r0) * K + c8;
  const __bf16* Bg = B + (size_t)(bn * 128 + r0) * K + c8;
  const int wr = (wave >> 1) * 64, wc = (wave & 1) * 64;
  const int fr = lane & 15, fk = (lane >> 4) * 8;
  const f32x4 fzero = {0.f, 0.f, 0.f, 0.f};
  f32x4 acc[4][4];
#pragma unroll
  for (int i = 0; i < 4; ++i)
#pragma unroll
    for (int j = 0; j < 4; ++j) acc[i][j] = fzero;

  load_lds16(Ag,                  &As[0][tid * 8]);
  load_lds16(Ag + (size_t)64 * K, &As[0][tid * 8 + 2048]);
  load_lds16(Bg,                  &Bs[0][tid * 8]);
  load_lds16(Bg + (size_t)64 * K, &Bs[0][tid * 8 + 2048]);

  int buf = 0;
  for (int k0 = 0; k0 < K; k0 += 32) {
    __syncthreads();   // drains own vmcnt -> buf's staging complete for all
    if (k0 + 32 < K) {
      const int nb = buf ^ 1;
      load_lds16(Ag + k0 + 32,                  &As[nb][tid * 8]);
      load_lds16(Ag + (size_t)64 * K + k0 + 32, &As[nb][tid * 8 + 2048]);
      load_lds16(Bg + k0 + 32,                  &Bs[nb][tid * 8]);
      load_lds16(Bg + (size_t)64 * K + k0 + 32, &Bs[nb][tid * 8 + 2048]);
    }
    bf16x8 af[4], bfg[4];
#pragma unroll
    for (int i = 0; i < 4; ++i) af[i]  = *(const bf16x8*)&As[buf][(wr + i * 16 + fr) * 32 + fk];
#pragma unroll
    for (int j = 0; j < 4; ++j) bfg[j] = *(const bf16x8*)&Bs[buf][(wc + j * 16 + fr) * 32 + fk];
#pragma unroll
    for (int i = 0; i < 4; ++i)
#pragma unroll
      for (int j = 0; j < 4; ++j)
        acc[i][j] = MFMA16(af[i], bfg[j], acc[i][j]);
    buf ^= 1;
  }
  const int rbase = (lane >> 4) * 4;
  float* Cb = C + (size_t)(bm * 128 + wr + rbase) * N + bn * 128 + wc + fr;
#pragma unroll
  for (int i = 0; i < 4; ++i)
#pragma unroll
    for (int j = 0; j < 4; ++j)
#pragma unroll
      for (int r = 0; r < 4; ++r)
        Cb[(size_t)(i * 16 + r) * N + j * 16] = acc[i][j][r];
}

// ---------------------------------------------------------------- merged Wq+Wkva GEMM
// R13-verified: one dispatch over N=2688 (WqT||WkvaT contiguous), plain f32
// epilogue branching on bn for dest/stride. Bit-identical to separate GEMMs.
__global__ __launch_bounds__(256) void k_gemm_qkva(const __bf16* __restrict__ A,
                                                   const __bf16* __restrict__ Bq,
                                                   float* __restrict__ q,
                                                   float* __restrict__ ckv) {
  const int K = 2048;
  __shared__ __align__(16) __bf16 As[2][128 * 32];
  __shared__ __align__(16) __bf16 Bs[2][128 * 32];
  const int tid  = threadIdx.x;
  const int lane = tid & 63;
  const int wave = tid >> 6;
  const int bm = blockIdx.x, bn = blockIdx.y;
  const int r0 = tid >> 2;
  const int c8 = (tid & 3) * 8;
  const __bf16* Ag = A  + (size_t)(bm * 128 + r0) * K + c8;
  const __bf16* Bg = Bq + (size_t)(bn * 128 + r0) * K + c8;
  const int wr = (wave >> 1) * 64, wc = (wave & 1) * 64;
  const int fr = lane & 15, fk = (lane >> 4) * 8;
  const f32x4 fzero = {0.f, 0.f, 0.f, 0.f};
  f32x4 acc[4][4];
#pragma unroll
  for (int i = 0; i < 4; ++i)
#pragma unroll
    for (int j = 0; j < 4; ++j) acc[i][j] = fzero;

  load_lds16(Ag,                  &As[0][tid * 8]);
  load_lds16(Ag + (size_t)64 * K, &As[0][tid * 8 + 2048]);
  load_lds16(Bg,                  &Bs[0][tid * 8]);
  load_lds16(Bg + (size_t)64 * K, &Bs[0][tid * 8 + 2048]);

  int buf = 0;
  for (int k0 = 0; k0 < K; k0 += 32) {
    __syncthreads();
    if (k0 + 32 < K) {
      const int nb = buf ^ 1;
      load_lds16(Ag + k0 + 32,                  &As[nb][tid * 8]);
      load_lds16(Ag + (size_t)64 * K + k0 + 32, &As[nb][tid * 8 + 2048]);
      load_lds16(Bg + k0 + 32,                  &Bs[nb][tid * 8]);
      load_lds16(Bg + (size_t)64 * K + k0 + 32, &Bs[nb][tid * 8 + 2048]);
    }
    bf16x8 af[4], bfg[4];
#pragma unroll
    for (int i = 0; i < 4; ++i) af[i]  = *(const bf16x8*)&As[buf][(wr + i * 16 + fr) * 32 + fk];
#pragma unroll
    for (int j = 0; j < 4; ++j) bfg[j] = *(const bf16x8*)&Bs[buf][(wc + j * 16 + fr) * 32 + fk];
#pragma unroll
    for (int i = 0; i < 4; ++i)
#pragma unroll
      for (int j = 0; j < 4; ++j)
        acc[i][j] = MFMA16(af[i], bfg[j], acc[i][j]);
    buf ^= 1;
  }
  const int rbase = (lane >> 4) * 4;
  float* Cb;
  int stride;
  if (bn < 16) { Cb = q   + (size_t)(bm * 128 + wr + rbase) * 2048 + bn * 128 + wc + fr;        stride = 2048; }
  else         { Cb = ckv + (size_t)(bm * 128 + wr + rbase) * NKVAP_ + (bn - 16) * 128 + wc + fr; stride = NKVAP_; }
#pragma unroll
  for (int i = 0; i < 4; ++i)
#pragma unroll
    for (int j = 0; j < 4; ++j)
#pragma unroll
      for (int r = 0; r < 4; ++r)
        Cb[(size_t)(i * 16 + r) * stride + j * 16] = acc[i][j][r];
}

// ---------------------------------------------------------------- fused rope_q + cast_kvl
// R14: both depend only on the qkva GEMM; one dispatch, both vectorized x8.
// Per-element FP ops and order identical to the scalar versions.
// Partition: 4096 (rope_q) + 1024 (cast_kvl) = 5120 blocks.
__global__ __launch_bounds__(256) void k_rope_cast(const float* __restrict__ q,
                                                   const float* __restrict__ ckv,
                                                   __bf16* __restrict__ qf,
                                                   __bf16* __restrict__ kvl) {
  const float scale2 = 1.4426950408889634f / 11.313708498984760f; // log2e/sqrt(128)
  const int id = blockIdx.x;
  const int tid = threadIdx.x;
  if (id < 4096) {
    // rope_q: 8 d-elems/thread over B*H*T*HD/8 = 1048576 threads
    const int idx = id * 256 + tid;
    const int d8 = (idx & 15) * 8;
    const int t  = (idx >> 4) & 2047;
    const int bh = idx >> 15;
    const int h = bh & 15, b = bh >> 4;
    const float* qrow = q + ((size_t)(b * T_ + t)) * 2048 + h * 128 + d8;
    float4 a = *(const float4*)qrow, bb = *(const float4*)(qrow + 4);
    float v[8] = {a.x, a.y, a.z, a.w, bb.x, bb.y, bb.z, bb.w};
    union { __bf16 h8[8]; bf16x8 vv; } o;
    if (d8 < 64) {
#pragma unroll
      for (int j = 0; j < 8; ++j) o.h8[j] = (__bf16)(v[j] * scale2);
    } else {
#pragma unroll
      for (int p = 0; p < 4; ++p) {
        const int i = ((d8 - 64) >> 1) + p;
        float freq = exp2f(-((float)(2 * i) / 64.0f) * LOG2_THETA);
        float ang = (float)t * freq;
        float c = cosf(ang), s = sinf(ang);
        float x0 = v[2 * p], x1 = v[2 * p + 1];
        o.h8[2 * p]     = (__bf16)((x0 * c - x1 * s) * scale2);
        o.h8[2 * p + 1] = (__bf16)((x0 * s + x1 * c) * scale2);
      }
    }
    *(bf16x8*)(qf + ((size_t)bh * T_ + t) * 128 + d8) = o.vv;
  } else {
    // cast_kvl: 8 elems/thread over BT*512/8 = 262144 threads
    const int idx = (id - 4096) * 256 + tid;
    const int r = idx >> 6, c8 = (idx & 63) * 8;
    const float* src = ckv + (size_t)r * NKVAP_ + c8;
    float4 a = *(const float4*)src, bb = *(const float4*)(src + 4);
    union { __bf16 h8[8]; bf16x8 vv; } o;
    o.h8[0] = (__bf16)a.x;  o.h8[1] = (__bf16)a.y;
    o.h8[2] = (__bf16)a.z;  o.h8[3] = (__bf16)a.w;
    o.h8[4] = (__bf16)bb.x; o.h8[5] = (__bf16)bb.y;
    o.h8[6] = (__bf16)bb.z; o.h8[7] = (__bf16)bb.w;
    *(bf16x8*)(kvl + (size_t)r * 512 + c8) = o.vv;
  }
}

// Fragment-packed K layout (consumed by the no-LDS attention kernel):
//   Kp[bh][tile][cg][kg][lane][8 bf16], tile = key>>6, cg = (key>>4)&3,
//   fr = key&15, kg = dim>>5, quad = (dim>>3)&3, e = dim&7, lane = quad*16+fr.
// Vp[bh][tile][g][ks][lane][8]: dim row = g*16+fr, key col = ks*32+quad*8+e.

// ---------------------------------------------------------------- fused pack_kv + rope_kf
// R17 FIX: rope_kf partition is B*H*T*8 = 524288 threads (4 pairs each) =
// 2048 blocks, NOT 4096. R14/R16's 4096 made idx>=524288 compute b in {2,3}:
// OOB ckv reads + Kp writes at bh 32..63 landing in Vp (absmax 1.83) and
// ~1KB past the q buffer (the nondeterministic container hangs).
// Partition: 1024 (pack_kv) + 2048 (rope_kf) = 3072 blocks.
__global__ __launch_bounds__(256) void k_pack(const float* __restrict__ kv,
                                              const float* __restrict__ ckv,
                                              __bf16* __restrict__ Kp,
                                              __bf16* __restrict__ Vp) {
  __shared__ float tile[64][65];
  const int id = blockIdx.x;
  const int tid = threadIdx.x;
  if (id < 1024) {
    // pack_kv: kv -> Kp nope dims (0..63) AND Vp
    const int bh = id & 31;
    const int t0 = (id >> 5) * 64;
    const int b = bh >> 4, h = bh & 15;
    const int tilei = t0 >> 6;
    const int i0 = tid >> 4, d4 = (tid & 15) * 4;
    const int kg = d4 >> 5, qd = (d4 >> 3) & 3, e = d4 & 7;   // dim coords
#pragma unroll
    for (int p = 0; p < 4; ++p) {
      int i = i0 + p * 16;                                    // key within tile
      const float* src = kv + ((size_t)(b * T_ + t0 + i)) * 1024 + h * 64 + d4;
      float4 v = *(const float4*)src;
      tile[i][d4] = v.x; tile[i][d4 + 1] = v.y; tile[i][d4 + 2] = v.z; tile[i][d4 + 3] = v.w;
      union { __bf16 hh[4]; uint2 u; } o;
      o.hh[0] = (__bf16)v.x; o.hh[1] = (__bf16)v.y; o.hh[2] = (__bf16)v.z; o.hh[3] = (__bf16)v.w;
      const int cg = i >> 4, frk = i & 15;
      size_t koff = (((size_t)(bh * 32 + tilei) * 16) + cg * 4 + kg) * 512
                  + (qd * 16 + frk) * 8 + e;
      *(uint2*)(Kp + koff) = o.u;
    }
    __syncthreads();
    const int dd = tid >> 2, tc0 = (tid & 3) * 16;
    __bf16 outv[16];
#pragma unroll
    for (int j = 0; j < 16; ++j) outv[j] = (__bf16)tile[tc0 + j][dd];
    const int g = dd >> 4, frv = dd & 15;
    const int ks = tc0 >> 5, qv = (tc0 >> 3) & 3;
    size_t voff = (((size_t)(bh * 32 + tilei) * 8) + g * 2 + ks) * 512
                + (qv * 16 + frv) * 8;
    *(bf16x8*)(Vp + voff) = *(bf16x8*)&outv[0];
    *(bf16x8*)(Vp + voff + 128) = *(bf16x8*)&outv[8]; // quad+1 -> +16*8 halfwords
  } else {
    // rope_kf: ckv cols [512,576) -> Kp rope dims, 4 pairs/thread
    const int idx = (id - 1024) * 256 + tid;   // over B*H*T*8 = 524288
    const int i4 = (idx & 7) * 4;              // pair group: i = i4..i4+3
    const int t = (idx >> 3) & 2047;
    const int h = (idx >> 14) & 15;
    const int b = idx >> 18;
    const float* src = ckv + ((size_t)(b * T_ + t)) * NKVAP_ + 512 + 2 * i4;
    float4 a = *(const float4*)src, bb = *(const float4*)(src + 4);
    float v[8] = {a.x, a.y, a.z, a.w, bb.x, bb.y, bb.z, bb.w};
    union { __bf16 h8[8]; bf16x8 vv; } o;
#pragma unroll
    for (int p = 0; p < 4; ++p) {
      const int i = i4 + p;
      float freq = exp2f(-((float)(2 * i) / 64.0f) * LOG2_THETA);
      float ang = (float)t * freq;
      float c = cosf(ang), s = sinf(ang);
      float x0 = v[2 * p], x1 = v[2 * p + 1];
      o.h8[2 * p]     = (__bf16)(x0 * c - x1 * s);
      o.h8[2 * p + 1] = (__bf16)(x0 * s + x1 * c);
    }
    const int bh = b * 16 + h;
    const int tilei = t >> 6, cg = (t >> 4) & 3, frk = t & 15;
    const int kg = 2 + (i4 >> 4), qd = (i4 >> 2) & 3;
    size_t off = (((size_t)(bh * 32 + tilei) * 16) + cg * 4 + kg) * 512
               + (qd * 16 + frk) * 8;
    *(bf16x8*)(Kp + off) = o.vv;
  }
}

// ---------------------------------------------------------------- attention
// R13-verified (323.7 total): load-balanced pairing (each block does qt=p and
// 31-p), 8 waves split-K (waves 0-3 even K-tiles, 4-7 odd), fragment-packed
// K/V direct from L2, online-softmax partials merged via 18KB LDS.
__global__ __launch_bounds__(512, 4) void k_attn(const __bf16* __restrict__ qf,
                                                 const __bf16* __restrict__ Kp,
                                                 const __bf16* __restrict__ Vp,
                                                 __bf16* __restrict__ yc) {
  const int blk = blockIdx.x;          // 512 = 16 pair * 32 bh
  const int bh = blk & 31;             // bh mod 8 == XCD -> per-XCD L2 locality
  const int p  = blk >> 5;             // tile pair: qt = p and 31-p
  const int b = bh >> 4, h = bh & 15;
  const int tid = threadIdx.x;
  const int lane = tid & 63, wave = tid >> 6;    // 0..7
  const int w4 = wave & 3, par = wave >> 2;      // q-row group, K-tile parity
  const int fr = lane & 15, quad = lane >> 4, fk8 = quad * 8;

  __shared__ __align__(16) f32x4 mrgO[4][64][4]; // 16 KB partial accO
  __shared__ float mrgML[4][64][2];              // 2 KB partial m,l

  const __bf16* kb = Kp + (size_t)bh * 32 * 8192 + (size_t)lane * 8;
  const __bf16* vb = Vp + (size_t)bh * 32 * 4096 + (size_t)lane * 8;
  const int srcA = (quad & 1) * 32 + fr, srcB = srcA + 16;
  const int hi = quad >> 1;
  const f32x4 fzero = {0.f, 0.f, 0.f, 0.f};

  auto process = [&](int qt) {
    const int qbase = qt * 64;
    const int qi = qbase + w4 * 16 + fr;         // this lane's q-row
    const __bf16* qb = qf + ((size_t)bh * T_ + qi) * HD_;
    bf16x8 aq[4];
#pragma unroll
    for (int g = 0; g < 4; ++g) aq[g] = *(const bf16x8*)(qb + g * 32 + fk8);

    f32x4 accO[4];
#pragma unroll
    for (int g = 0; g < 4; ++g) accO[g] = fzero;
    float m = -1e30f, l = 0.f;

    for (int s0 = par * 64; s0 <= qbase; s0 += 128) {
      const __bf16* kt = kb + (size_t)(s0 >> 6) * 8192;
      const __bf16* vt = vb + (size_t)(s0 >> 6) * 4096;

      // K fragments: 16 coalesced 1KB loads
      bf16x8 kr[4][4];
#pragma unroll
      for (int cg = 0; cg < 4; ++cg)
#pragma unroll
        for (int kg = 0; kg < 4; ++kg)
          kr[cg][kg] = *(const bf16x8*)(kt + (cg * 4 + kg) * 512);

      // S^T: rows = keys (quad*4+r), cols = q (fr)
      f32x4 accST[4];
#pragma unroll
      for (int cg = 0; cg < 4; ++cg) accST[cg] = fzero;
      __builtin_amdgcn_s_setprio(1);
#pragma unroll
      for (int cg = 0; cg < 4; ++cg) {
#pragma unroll
        for (int kg = 0; kg < 4; ++kg)
          accST[cg] = MFMA16(kr[cg][kg], aq[kg], accST[cg]);
      }
      __builtin_amdgcn_s_setprio(0);

      // V fragments issued now; latency hides under the softmax VALU phase
      bf16x8 vr[4][2];
#pragma unroll
      for (int g = 0; g < 4; ++g)
#pragma unroll
        for (int ks = 0; ks < 2; ++ks)
          vr[g][ks] = *(const bf16x8*)(vt + (g * 2 + ks) * 512);

      // row max (mask only on the diagonal tile; values pre-scaled via qf)
      float lmax = -1e30f;
      if (s0 == qbase) {
#pragma unroll
        for (int cg = 0; cg < 4; ++cg) {
#pragma unroll
          for (int r = 0; r < 4; ++r) {
            const int key = s0 + cg * 16 + quad * 4 + r;
            float v = accST[cg][r];
            v = (key <= qi) ? v : -1e30f;
            accST[cg][r] = v;
            lmax = fmaxf(lmax, v);
          }
        }
      } else {
#pragma unroll
        for (int cg = 0; cg < 4; ++cg) {
#pragma unroll
          for (int r = 0; r < 4; ++r) lmax = fmaxf(lmax, accST[cg][r]);
        }
      }
      lmax = fmaxf(lmax, __shfl_xor(lmax, 16, 64));
      lmax = fmaxf(lmax, __shfl_xor(lmax, 32, 64));

      // T13 defer-max: only rescale when the running max grew by > 8
      if (!__all(lmax <= m + 8.0f)) {
        const float mn = fmaxf(m, lmax);
        const float alpha = exp2f(m - mn);
        l *= alpha;
#pragma unroll
        for (int g = 0; g < 4; ++g)
#pragma unroll
          for (int r = 0; r < 4; ++r) accO[g][r] *= alpha;
        m = mn;
      }

      float lsum = 0.f;
      unsigned pk0[4], pk1[4];
#pragma unroll
      for (int cg = 0; cg < 4; ++cg) {
        float p0 = exp2f(accST[cg][0] - m);
        float p1 = exp2f(accST[cg][1] - m);
        float p2 = exp2f(accST[cg][2] - m);
        float p3 = exp2f(accST[cg][3] - m);
        lsum += (p0 + p1) + (p2 + p3);
        pk0[cg] = pkbf(p0, p1);
        pk1[cg] = pkbf(p2, p3);
      }
      lsum += __shfl_xor(lsum, 16, 64);
      lsum += __shfl_xor(lsum, 32, 64);
      l += lsum;

      // PV: B-operand (P) built from register shuffles
#pragma unroll
      for (int ks = 0; ks < 2; ++ks) {
        int a0 = __shfl((int)pk0[2 * ks], srcA, 64);
        int b0 = __shfl((int)pk0[2 * ks + 1], srcA, 64);
        int a1 = __shfl((int)pk1[2 * ks], srcA, 64);
        int b1 = __shfl((int)pk1[2 * ks + 1], srcA, 64);
        int a2 = __shfl((int)pk0[2 * ks], srcB, 64);
        int b2 = __shfl((int)pk0[2 * ks + 1], srcB, 64);
        int a3 = __shfl((int)pk1[2 * ks], srcB, 64);
        int b3 = __shfl((int)pk1[2 * ks + 1], srcB, 64);
        union { int i[4]; bf16x8 v; } pf;
        pf.i[0] = hi ? b0 : a0;
        pf.i[1] = hi ? b1 : a1;
        pf.i[2] = hi ? b2 : a2;
        pf.i[3] = hi ? b3 : a3;
        __builtin_amdgcn_s_setprio(1);
#pragma unroll
        for (int g = 0; g < 4; ++g)
          accO[g] = MFMA16(vr[g][ks], pf.v, accO[g]);
        __builtin_amdgcn_s_setprio(0);
      }
    }

    // split-K merge: odd-parity publish partials, even-parity merge+store
    if (par) {
#pragma unroll
      for (int g = 0; g < 4; ++g) mrgO[w4][lane][g] = accO[g];
      mrgML[w4][lane][0] = m;
      mrgML[w4][lane][1] = l;
    }
    __syncthreads();
    if (!par) {
      const float m1 = mrgML[w4][lane][0];
      const float l1 = mrgML[w4][lane][1];
      const float mn = fmaxf(m, m1);
      const float a0 = exp2f(m - mn), a1 = exp2f(m1 - mn);
      const float lt = l * a0 + l1 * a1;
      const float linv = 1.0f / lt;
      // epilogue: O^T -> yc[(b*T+qi)*1024 + h*64 + d], d = g*16+quad*4+r
      __bf16* yb = yc + ((size_t)(b * T_ + qi)) * 1024 + h * 64 + quad * 4;
#pragma unroll
      for (int g = 0; g < 4; ++g) {
        f32x4 o1 = mrgO[w4][lane][g];
        union { unsigned u[2]; uint2 v; } o;
        o.u[0] = pkbf((accO[g][0] * a0 + o1[0] * a1) * linv,
                      (accO[g][1] * a0 + o1[1] * a1) * linv);
        o.u[1] = pkbf((accO[g][2] * a0 + o1[2] * a1) * linv,
                      (accO[g][3] * a0 + o1[3] * a1) * linv);
        *(uint2*)(yb + g * 16) = o.v;
      }
    }
  };

  process(p);
  __syncthreads();      // protect merge-LDS reuse between the two passes
  process(31 - p);
}

// ---------------------------------------------------------------- launch
extern "C" void kernel_launch(void* const* d_in, const int* in_sizes, int n_in,
                              void* d_out, int out_size, void* d_ws, size_t ws_size,
                              hipStream_t stream) {
  const float* x    = (const float*)d_in[0];
  const float* Wq   = (const float*)d_in[1];
  const float* Wkva = (const float*)d_in[2];
  const float* Wkvb = (const float*)d_in[3];
  const float* Wo   = (const float*)d_in[4];
  float* out = (float*)d_out;
  char* ws = (char*)d_ws;

  // workspace layout (bytes)
  size_t off = 0;
  __bf16* xb    = (__bf16*)(ws + off); off += (size_t)BT_ * C_ * 2;          // 16.78M
  __bf16* WqT   = (__bf16*)(ws + off); off += (size_t)2048 * 2048 * 2;       // 8.39M
  __bf16* WkvaT = (__bf16*)(ws + off); off += (size_t)NKVAP_ * 2048 * 2;     // 2.62M (contiguous after WqT -> combined B, 2688 rows)
  __bf16* WkvbT = (__bf16*)(ws + off); off += (size_t)1024 * 512 * 2;        // 1.05M
  __bf16* WoTc  = (__bf16*)(ws + off); off += (size_t)2048 * 1024 * 2;       // 4.19M
  float*  q     = (float*)(ws + off);  off += (size_t)BT_ * 2048 * 4;        // 33.55M
  float*  ckv   = (float*)(ws + off);  off += (size_t)BT_ * NKVAP_ * 4;      // 10.49M
  __bf16* kvl   = (__bf16*)(ws + off); off += (size_t)BT_ * 512 * 2;         // 4.19M
  float*  kv    = (float*)(ws + off);  off += (size_t)BT_ * 1024 * 4;        // 16.78M
  __bf16* qfb   = (__bf16*)(ws + off); off += (size_t)B_ * H_ * T_ * HD_ * 2;// 16.78M
  __bf16* yc    = (__bf16*)(ws + off); off += (size_t)BT_ * 1024 * 2;        // 8.39M
  // Kp (16.78M) and Vp (8.39M) alias q's 33.55M buffer: q is dead after
  // k_rope_cast, and both are written strictly after it in stream order.
  __bf16* Kp = (__bf16*)q;
  __bf16* Vp = (__bf16*)((char*)q + (size_t)B_ * H_ * T_ * HD_ * 2);

  // 1. fused prologue: cast_x + 4 weight transposes (one dispatch)
  k_prep<<<12032, 256, 0, stream>>>(x, Wq, Wkva, Wkvb, Wo, xb, WqT, WkvaT, WkvbT, WoTc);

  // 2. merged Wq+Wkva projection (N=2688)
  k_gemm_qkva<<<dim3(BT_ / 128, 2688 / 128), 256, 0, stream>>>(xb, WqT, q, ckv);

  // 3. fused rope_q + cast_kvl (vectorized x8)
  k_rope_cast<<<5120, 256, 0, stream>>>(q, ckv, qfb, kvl);

  // 4. kv up-projection, then fused pack_kv + rope_kf (1024 + 2048 blocks)
  k_gemm_bt<<<dim3(BT_ / 128, 1024 / 128), 256, 0, stream>>>(kvl, WkvbT, kv, BT_, 1024, 512);
  k_pack<<<3072, 256, 0, stream>>>(kv, ckv, Kp, Vp);

  // 5. attention (512 blocks x 512 threads; each block does qt=p and 31-p)
  k_attn<<<(T_ / 128) * B_ * H_, 512, 0, stream>>>(qfb, Kp, Vp, yc);

  // 6. output projection
  k_gemm_bt<<<dim3(BT_ / 128, 2048 / 128), 256, 0, stream>>>(yc, WoTc, out, BT_, 2048, 1024);
}